// Round 6
// baseline (748.913 us; speedup 1.0000x reference)
//
#include <hip/hip_runtime.h>

// ---------------------------------------------------------------------------
// RWKV6 Tmix (B=4,T=2048,C=2048,H=32,HS=64). Inputs fp32, OUTPUT FP32.
// Round 6: chunked linear-attention wkv. Round 7: parallel chunk recurrence.
// Round 8/9: 256x256-tile 8-phase GEMM for the two K=2048 GEMMs.
// Round 10: mix5_k fusion + prep_k merge.
// Round 11: (a) mix5_k epilogue -> LDS out-staging + 16B coalesced stores
// (320 scalar 2B stores/thread -> 40 wide), counted vmcnt(8) instead of
// vmcnt(0) drain between outputs (stores no longer serialize the 5 rounds);
// (b) the two skinny tanh GEMMs (N=128, N=32) merged into one grid(64,2)
// launch so they run concurrently (each alone fills only 25% of CUs).
// ---------------------------------------------------------------------------

#define Cdim 2048
#define Tdim 2048

using short8 = __attribute__((ext_vector_type(8))) short;   // 8 x bf16
using f32x4  = __attribute__((ext_vector_type(4))) float;
using us4    = __attribute__((ext_vector_type(4))) unsigned short;
typedef unsigned short ushort_t;

__device__ __forceinline__ float b2f(unsigned short h) {
    union { unsigned int u; float f; } x; x.u = ((unsigned int)h) << 16; return x.f;
}
__device__ __forceinline__ unsigned short f2b(float f) {
    union { float f; unsigned int u; } x; x.f = f;
    unsigned int r = x.u + 0x7fffu + ((x.u >> 16) & 1u);   // RNE
    return (unsigned short)(r >> 16);
}

__device__ __forceinline__ void gload16(const void* g, void* l) {
    __builtin_amdgcn_global_load_lds(
        (__attribute__((address_space(1))) void*)g,
        (__attribute__((address_space(3))) void*)l, 16, 0, 0);
}

// ---------------------------------------------------------------------------
// prep_k: fp32->bf16 convert (x_in, value_w, output_w) + all weight
// transposes (fp32 -> bf16 transposed), one launch.
// ---------------------------------------------------------------------------
__global__ __launch_bounds__(256) void prep_k(
    const float* __restrict__ x_in, const float* __restrict__ valw,
    const float* __restrict__ outw,
    ushort_t* __restrict__ xinB, ushort_t* __restrict__ valwB,
    ushort_t* __restrict__ outwB,
    const float* __restrict__ w1,  const float* __restrict__ ww1,
    const float* __restrict__ dw1, const float* __restrict__ dw2,
    const float* __restrict__ ww2, const float* __restrict__ w2,
    ushort_t* __restrict__ w1T,  ushort_t* __restrict__ ww1T,
    ushort_t* __restrict__ dw1T, ushort_t* __restrict__ dw2T,
    ushort_t* __restrict__ ww2T, ushort_t* __restrict__ w2T)
{
    size_t g = (size_t)blockIdx.x * 256 + threadIdx.x;
    if (g < 6291456) {
        const float* src; ushort_t* dst; size_t e;
        if (g < 4194304)      { src = x_in; dst = xinB;  e = g; }
        else if (g < 5242880) { src = valw; dst = valwB; e = g - 4194304; }
        else                  { src = outw; dst = outwB; e = g - 5242880; }
        const float4 v = ((const float4*)src)[e];
        us4 o; o.x = f2b(v.x); o.y = f2b(v.y); o.z = f2b(v.z); o.w = f2b(v.w);
        ((us4*)dst)[e] = o;
        return;
    }
    int idx = (int)(g - 6291456);
    if (idx < 262144) { int r = idx >> 7, c = idx & 127; w1T[c * 2048 + r] = f2b(w1[idx]); return; }
    idx -= 262144;
    if (idx < 65536)  { int r = idx >> 5, c = idx & 31;  ww1T[c * 2048 + r] = f2b(ww1[idx]); return; }
    idx -= 65536;
    if (idx < 262144) { int r = idx >> 7, c = idx & 127; dw1T[c * 2048 + r] = f2b(dw1[idx]); return; }
    idx -= 262144;
    if (idx < 262144) { int r = idx >> 11, c = idx & 2047; dw2T[c * 128 + r] = f2b(dw2[idx]); return; }
    idx -= 262144;
    if (idx < 65536)  { int r = idx >> 11, c = idx & 2047; ww2T[c * 32 + r] = f2b(ww2[idx]); return; }
    idx -= 65536;
    { int f = idx >> 16, rem = idx & 65535; int r = rem >> 11, c = rem & 2047;
      w2T[f * 65536 + c * 32 + r] = f2b(w2[idx]); }
}

// ---------------------------------------------------------------------------
// 256x256-tile 8-phase GEMM, M=8192 N=2048 K=2048, C = A @ B^T (both bf16
// row-major, ld=2048). MODE 2: bf16 store; MODE 5: fp32 store. (round 8/9)
// ---------------------------------------------------------------------------
template <int MODE>
__global__ __launch_bounds__(512, 2) void gemm256_k(
    const ushort_t* __restrict__ A,
    const ushort_t* __restrict__ Bw,
    ushort_t* __restrict__ outB,
    float* __restrict__ outF)
{
    __shared__ __align__(16) ushort_t lds[65536];   // A: [0,32768) B: [32768,65536)

    const int tid  = threadIdx.x;
    const int wave = tid >> 6, lane = tid & 63;
    const int wm = wave >> 2, wn = wave & 3;        // 2M x 4N wave grid
    const int fr = lane & 15, quad = lane >> 4;
    const int og8 = (((lane & 7) ^ ((lane >> 3) & 7)) * 8);

    const int id  = blockIdx.x;
    const int swz = (id & 7) * 32 + (id >> 3);
    const int mbase = (swz >> 3) * 256;             // 32 m-tiles
    const int nbase = (swz & 7) * 256;              // 8 n-tiles

    f32x4 acc[8][4];
#pragma unroll
    for (int i = 0; i < 8; ++i)
#pragma unroll
        for (int j = 0; j < 4; ++j)
#pragma unroll
            for (int r = 0; r < 4; ++r) acc[i][j][r] = 0.f;

    auto stage_half = [&](const ushort_t* __restrict__ G, int growb,
                          int dstb, int kt) {
#pragma unroll
        for (int i = 0; i < 2; ++i) {
            const int rh = i * 64 + wave * 8 + (lane >> 3);
            gload16(G + (size_t)(growb + rh) * Cdim + kt * 64 + og8,
                    &lds[dstb + (i * 512 + wave * 64) * 8]);
        }
    };

    short8 afr[4][2], bfr[2][2];

    auto LOADA = [&](int p, int mo) {
#pragma unroll
        for (int mi = 0; mi < 4; ++mi)
#pragma unroll
            for (int k = 0; k < 2; ++k) {
                const int row = wm * 128 + (mo + mi) * 16 + fr;
                afr[mi][k] = *(const short8*)
                    &lds[p + row * 64 + (((k * 4 + quad) ^ (fr & 7)) * 8)];
            }
    };
    auto LOADB = [&](int p, int no) {
#pragma unroll
        for (int ni = 0; ni < 2; ++ni)
#pragma unroll
            for (int k = 0; k < 2; ++k) {
                const int row = wn * 64 + (no + ni) * 16 + fr;
                bfr[ni][k] = *(const short8*)
                    &lds[32768 + p + row * 64 + (((k * 4 + quad) ^ (fr & 7)) * 8)];
            }
    };
    auto MFMA16 = [&](int mo, int no) {
        __builtin_amdgcn_s_setprio(1);
#pragma unroll
        for (int mi = 0; mi < 4; ++mi)
#pragma unroll
            for (int ni = 0; ni < 2; ++ni)
#pragma unroll
                for (int k = 0; k < 2; ++k)
                    acc[mo + mi][no + ni] = __builtin_amdgcn_mfma_f32_16x16x32_bf16(
                        afr[mi][k], bfr[ni][k], acc[mo + mi][no + ni], 0, 0, 0);
        __builtin_amdgcn_s_setprio(0);
    };

    // prologue: tile 0 -> buf 0
    stage_half(A,  mbase,       0,            0);
    stage_half(A,  mbase + 128, 8192,         0);
    stage_half(Bw, nbase,       32768,        0);
    stage_half(Bw, nbase + 128, 32768 + 8192, 0);

#pragma unroll 2
    for (int t = 0; t < 32; ++t) {
        const int p  = (t & 1) * 16384;      // compute buffer (element offset)
        const int q  = 16384 - p;            // stage buffer
        const int kn = (t < 31) ? t + 1 : t; // clamped prefetch tile

        // ---- P1: m[0..3] x n[0..1]; stage A(t+1) ----
        asm volatile("s_waitcnt vmcnt(0)\n\ts_barrier" ::: "memory");
        LOADA(p, 0); LOADB(p, 0);
        stage_half(A, mbase,       q,        kn);
        stage_half(A, mbase + 128, q + 8192, kn);
        asm volatile("s_barrier" ::: "memory");
        asm volatile("s_waitcnt lgkmcnt(0)" ::: "memory");
        MFMA16(0, 0);

        // ---- P2: m[0..3] x n[2..3]; stage B(t+1) ----
        asm volatile("s_barrier" ::: "memory");
        LOADB(p, 2);
        stage_half(Bw, nbase,       32768 + q,        kn);
        stage_half(Bw, nbase + 128, 32768 + q + 8192, kn);
        asm volatile("s_barrier" ::: "memory");
        asm volatile("s_waitcnt lgkmcnt(0)" ::: "memory");
        MFMA16(0, 2);

        // ---- P3: m[4..7] x n[2..3] ----
        asm volatile("s_barrier" ::: "memory");
        LOADA(p, 4);
        asm volatile("s_barrier" ::: "memory");
        asm volatile("s_waitcnt lgkmcnt(0)" ::: "memory");
        MFMA16(4, 2);

        // ---- P4: m[4..7] x n[0..1] ----
        asm volatile("s_barrier" ::: "memory");
        LOADB(p, 0);
        asm volatile("s_barrier" ::: "memory");
        asm volatile("s_waitcnt lgkmcnt(0)" ::: "memory");
        MFMA16(4, 0);
    }

    const int row0 = mbase + wm * 128 + quad * 4;
    const int col0 = nbase + wn * 64 + fr;
#pragma unroll
    for (int mi = 0; mi < 8; ++mi)
#pragma unroll
        for (int ni = 0; ni < 4; ++ni)
#pragma unroll
            for (int r = 0; r < 4; ++r) {
                const int row = row0 + mi * 16 + r;
                const int col = col0 + ni * 16;
                const size_t idx = (size_t)row * Cdim + col;
                if constexpr (MODE == 2) outB[idx] = f2b(acc[mi][ni][r]);
                else                     outF[idx] = acc[mi][ni][r];
            }
}

// ---------------------------------------------------------------------------
// mix5_k (round 11): five K=32 token-shift mix GEMMs fused, coalesced output.
// Block = 128x128 tile, 4 waves. x tile (+shifted row) in LDS once. Per
// output o: {fragments from abuf/bbuf, stage(o+1), 16 MFMA, epilogue ->
// outstage LDS (two 64-row halves) -> 16B cooperative stores}. Loop-top wait
// is vmcnt(8): stage loads (issued before the 8 stores) retire in-order, so
// outstanding<=8 proves loads landed without draining stores.
// Arithmetic bit-identical to round-10 (LDS passthrough of bf16 bytes).
// ---------------------------------------------------------------------------
__global__ __launch_bounds__(256) void mix5_k(
    const ushort_t* __restrict__ xxx,   // [8192][128] bf16
    const ushort_t* __restrict__ mwpre, // [8192][32]  bf16
    const ushort_t* __restrict__ w2T,   // 4x [2048][32] bf16
    const ushort_t* __restrict__ ww2T,  // [2048][32] bf16
    const ushort_t* __restrict__ xB,    // [8192][2048] bf16
    const float*    __restrict__ shiftS,// [4][2048] fp32
    const float* __restrict__ maa_r, const float* __restrict__ maa_k,
    const float* __restrict__ maa_v, const float* __restrict__ maa_v2,
    const float* __restrict__ maa_w,
    const float* __restrict__ recep, const float* __restrict__ tkey,
    ushort_t* __restrict__ mR,  ushort_t* __restrict__ mK,
    ushort_t* __restrict__ mV,  ushort_t* __restrict__ mV2,
    ushort_t* __restrict__ xwB)
{
    __shared__ __align__(16) ushort_t xs[129 * 136];     // [1+row][col]
    __shared__ __align__(16) ushort_t abuf[128 * 32];
    __shared__ __align__(16) ushort_t bbuf[128 * 32];
    __shared__ __align__(16) ushort_t outst[64 * 136];   // half-tile staging

    const int tid  = threadIdx.x;
    const int wave = tid >> 6, lane = tid & 63;
    const int wm = wave >> 1, wn = wave & 1;
    const int fr = lane & 15, quad = lane >> 4;

    const int mbase = blockIdx.x * 128;
    const int nbase = blockIdx.y * 128;
    const int b  = mbase >> 11;          // batch
    const int t0 = mbase & 2047;         // first t of tile

    // ---- stage x tile: xs[1+r][c] = xB[mbase+r][nbase+c] ----
#pragma unroll
    for (int it = 0; it < 8; ++it) {
        const int idx = it * 256 + tid;          // [0,2048)
        const int r = idx >> 4, c8 = (idx & 15) * 8;
        *(short8*)&xs[(r + 1) * 136 + c8] =
            *(const short8*)&xB[(size_t)(mbase + r) * Cdim + nbase + c8];
    }
    if (tid < 128)
        xs[tid] = (t0 > 0) ? xB[(size_t)(mbase - 1) * Cdim + nbase + tid]
                           : f2b(shiftS[(size_t)b * Cdim + nbase + tid]);

    const ushort_t* asrc[5] = {xxx, xxx + 32, xxx + 64, xxx + 96, mwpre};
    const int       alda[5] = {128, 128, 128, 128, 32};
    const ushort_t* bsrc[5] = {w2T, w2T + 65536, w2T + 131072, w2T + 196608, ww2T};
    const float*    cvec[5] = {maa_r, maa_k, maa_v, maa_v2, maa_w};
    const float*    cmul[5] = {recep, tkey, nullptr, nullptr, nullptr};
    ushort_t*       outs[5] = {mR, mK, mV, mV2, xwB};

    // stage A_o/B_o 128x32: linear LDS dest, source octet pre-swizzled
    auto stageAB = [&](int o) {
#pragma unroll
        for (int i = 0; i < 2; ++i) {
            const int slot = i * 256 + tid;      // [0,512)
            const int r = slot >> 2, oct = slot & 3;
            const int sw = ((oct ^ (r & 3)) * 8);
            gload16(asrc[o] + (size_t)(mbase + r) * alda[o] + sw, &abuf[slot * 8]);
            gload16(bsrc[o] + (size_t)(nbase + r) * 32 + sw,      &bbuf[slot * 8]);
        }
    };

    stageAB(0);
    __syncthreads();    // drains vm (stage 0) + lgkm (xs writes)

    const int row0l = wm * 64 + quad * 4;
    const int col0l = wn * 64 + fr;

#pragma unroll
    for (int o = 0; o < 5; ++o) {
        // ---- fragments from abuf/bbuf ----
        short8 af[4], bf[4];
#pragma unroll
        for (int mi = 0; mi < 4; ++mi) {
            const int r = wm * 64 + mi * 16 + fr;
            af[mi] = *(const short8*)&abuf[r * 32 + ((quad ^ (r & 3)) * 8)];
        }
#pragma unroll
        for (int ni = 0; ni < 4; ++ni) {
            const int r = wn * 64 + ni * 16 + fr;
            bf[ni] = *(const short8*)&bbuf[r * 32 + ((quad ^ (r & 3)) * 8)];
        }
        asm volatile("s_waitcnt lgkmcnt(0)" ::: "memory");
        __builtin_amdgcn_sched_barrier(0);
        asm volatile("s_barrier" ::: "memory");   // all waves done reading bufs
        if (o < 4) stageAB(o + 1);                // 4 loads, before the stores

        f32x4 acc[4][4];
#pragma unroll
        for (int mi = 0; mi < 4; ++mi)
#pragma unroll
            for (int ni = 0; ni < 4; ++ni) {
#pragma unroll
                for (int r = 0; r < 4; ++r) acc[mi][ni][r] = 0.f;
                acc[mi][ni] = __builtin_amdgcn_mfma_f32_16x16x32_bf16(
                    af[mi], bf[ni], acc[mi][ni], 0, 0, 0);
            }

        // ---- epilogue: val -> outstage half-tile -> 16B coalesced stores ----
        const float* cv = cvec[o];
        const float* cm = cmul[o];
        ushort_t* op = outs[o];
#pragma unroll
        for (int h = 0; h < 2; ++h) {
            if (wm == h) {
#pragma unroll
                for (int mi = 0; mi < 4; ++mi)
#pragma unroll
                    for (int ni = 0; ni < 4; ++ni) {
                        const int lc = col0l + ni * 16;
                        const int col = nbase + lc;
#pragma unroll
                        for (int r = 0; r < 4; ++r) {
                            const int lr = row0l + mi * 16 + r;   // wm==h half
                            const float x  = b2f(xs[(lr + 1) * 136 + lc]);
                            const float xp = (lr == 0 && t0 == 0)
                                                 ? shiftS[(size_t)b * Cdim + col]
                                                 : b2f(xs[lr * 136 + lc]);
                            float val = x + (xp - x) * (cv[col] + acc[mi][ni][r]);
                            if (cm) val *= cm[col];
                            outst[(lr - h * 64) * 136 + lc] = f2b(val);
                        }
                    }
            }
            asm volatile("s_waitcnt lgkmcnt(0)" ::: "memory");
            asm volatile("s_barrier" ::: "memory");
#pragma unroll
            for (int i = 0; i < 4; ++i) {
                const int idx = i * 256 + tid;        // [0,1024)
                const int row = idx >> 4, c8 = (idx & 15) * 8;
                *(short8*)&op[(size_t)(mbase + h * 64 + row) * Cdim + nbase + c8] =
                    *(const short8*)&outst[row * 136 + c8];
            }
            asm volatile("s_barrier" ::: "memory");   // before outstage reuse
        }
        if (o < 4) {
            // loads (older) done when outstanding <= 8 queued stores
            asm volatile("s_waitcnt vmcnt(8)\n\ts_barrier" ::: "memory");
        }
    }
}

// ---------------------------------------------------------------------------
// tanh2_k (round 11): the two skinny tanh GEMMs in one launch, grid (64,2).
// by=0: xxx  = tanh(x_in @ maa_w1)   N=128, ldc=128
// by=1: mwpre= tanh(x    @ maa_w_w1) N=32,  ldc=32
// Body identical to the old MODE-1 gemm_bt (same clamp) -> bit-identical.
// ---------------------------------------------------------------------------
__global__ __launch_bounds__(256) void tanh2_k(
    const ushort_t* __restrict__ xinB, const ushort_t* __restrict__ w1T,
    const ushort_t* __restrict__ xB,   const ushort_t* __restrict__ ww1T,
    ushort_t* __restrict__ xxx, ushort_t* __restrict__ mwpre)
{
    const int by = blockIdx.y;
    const ushort_t* A  = by ? xB    : xinB;
    const ushort_t* Bw = by ? ww1T  : w1T;
    ushort_t* out      = by ? mwpre : xxx;
    const int N        = by ? 32 : 128;
    const int ldc      = N;

    __shared__ __align__(16) ushort_t At[128 * 32];
    __shared__ __align__(16) ushort_t Bt[128 * 32];

    const int tid  = threadIdx.x;
    const int wave = tid >> 6, lane = tid & 63;
    const int wm = wave >> 1, wn = wave & 1;
    const int fr = lane & 15, quad = lane >> 4;
    const int cr = lane >> 2;
    const int cc = (lane & 3) * 8;

    f32x4 acc[4][4];
#pragma unroll
    for (int i = 0; i < 4; ++i)
#pragma unroll
        for (int j = 0; j < 4; ++j)
#pragma unroll
            for (int r = 0; r < 4; ++r) acc[i][j][r] = 0.f;

    const int mbase = blockIdx.x * 128;

    for (int k0 = 0; k0 < 2048; k0 += 32) {
        __syncthreads();
#pragma unroll
        for (int c2 = 0; c2 < 2; ++c2) {
            const int q  = wave * 2 + c2;
            const int ar = mbase + q * 16 + cr;
            gload16(A + (size_t)ar * 2048 + k0 + cc, &At[q * 512]);
            int br = q * 16 + cr;
            br = br < N ? br : N - 1;   // clamp for skinny-N
            gload16(Bw + (size_t)br * 2048 + k0 + cc, &Bt[q * 512]);
        }
        __syncthreads();

        short8 af[4], bfr[4];
#pragma unroll
        for (int mi = 0; mi < 4; ++mi)
            af[mi] = *(const short8*)&At[(wm * 64 + mi * 16 + fr) * 32 + quad * 8];
#pragma unroll
        for (int ni = 0; ni < 4; ++ni)
            bfr[ni] = *(const short8*)&Bt[(wn * 64 + ni * 16 + fr) * 32 + quad * 8];
#pragma unroll
        for (int mi = 0; mi < 4; ++mi)
#pragma unroll
            for (int ni = 0; ni < 4; ++ni)
                acc[mi][ni] = __builtin_amdgcn_mfma_f32_16x16x32_bf16(
                    af[mi], bfr[ni], acc[mi][ni], 0, 0, 0);
    }

    const int row0 = mbase + wm * 64 + quad * 4;
    const int col0 = wn * 64 + fr;
#pragma unroll
    for (int mi = 0; mi < 4; ++mi)
#pragma unroll
        for (int ni = 0; ni < 4; ++ni) {
            const int col = col0 + ni * 16;
#pragma unroll
            for (int r = 0; r < 4; ++r) {
                const int row = row0 + mi * 16 + r;
                if (col < N)
                    out[(size_t)row * ldc + col] = f2b(tanhf(acc[mi][ni][r]));
            }
        }
}

// ---------------------------------------------------------------------------
// BT GEMM (128-tile): MODE 1: tanh (guarded); MODE 3: decay fuse.
// ---------------------------------------------------------------------------
template <int MODE>
__global__ __launch_bounds__(256) void gemm_bt_k(
    const ushort_t* __restrict__ A, int lda,
    const ushort_t* __restrict__ Bw, int ldb,
    int N, int K,
    ushort_t* __restrict__ outB, int ldc,
    const float* __restrict__ cvec,
    ushort_t* __restrict__ inplace)
{
    __shared__ __align__(16) ushort_t At[128 * 32];
    __shared__ __align__(16) ushort_t Bt[128 * 32];

    const int tid  = threadIdx.x;
    const int wave = tid >> 6, lane = tid & 63;
    const int wm = wave >> 1, wn = wave & 1;
    const int fr = lane & 15, quad = lane >> 4;
    const int cr = lane >> 2;
    const int cc = (lane & 3) * 8;

    f32x4 acc[4][4];
#pragma unroll
    for (int i = 0; i < 4; ++i)
#pragma unroll
        for (int j = 0; j < 4; ++j)
#pragma unroll
            for (int r = 0; r < 4; ++r) acc[i][j][r] = 0.f;

    const int mbase = blockIdx.x * 128;
    const int nbase = blockIdx.y * 128;

    for (int k0 = 0; k0 < K; k0 += 32) {
        __syncthreads();
#pragma unroll
        for (int c2 = 0; c2 < 2; ++c2) {
            const int q  = wave * 2 + c2;
            const int ar = mbase + q * 16 + cr;
            gload16(A + (size_t)ar * lda + k0 + cc, &At[q * 512]);
            int br = nbase + q * 16 + cr;
            br = br < N ? br : N - 1;
            gload16(Bw + (size_t)br * ldb + k0 + cc, &Bt[q * 512]);
        }
        __syncthreads();

        short8 af[4], bfr[4];
#pragma unroll
        for (int mi = 0; mi < 4; ++mi)
            af[mi] = *(const short8*)&At[(wm * 64 + mi * 16 + fr) * 32 + quad * 8];
#pragma unroll
        for (int ni = 0; ni < 4; ++ni)
            bfr[ni] = *(const short8*)&Bt[(wn * 64 + ni * 16 + fr) * 32 + quad * 8];
#pragma unroll
        for (int mi = 0; mi < 4; ++mi)
#pragma unroll
            for (int ni = 0; ni < 4; ++ni)
                acc[mi][ni] = __builtin_amdgcn_mfma_f32_16x16x32_bf16(
                    af[mi], bfr[ni], acc[mi][ni], 0, 0, 0);
    }

    const int row0 = mbase + wm * 64 + quad * 4;
    const int col0 = nbase + wn * 64 + fr;
#pragma unroll
    for (int mi = 0; mi < 4; ++mi) {
#pragma unroll
        for (int ni = 0; ni < 4; ++ni) {
            const int col = col0 + ni * 16;
#pragma unroll
            for (int r = 0; r < 4; ++r) {
                const int row = row0 + mi * 16 + r;
                const float v = acc[mi][ni][r];
                const size_t idx = (size_t)row * ldc + col;
                if constexpr (MODE == 1) {
                    if (col < N) outB[idx] = f2b(tanhf(v));
                } else {  // MODE 3
                    const float w  = cvec[col] + v;
                    const float ew = __expf(w);
                    outB[idx] = f2b(ew);
                    inplace[idx] = f2b(b2f(inplace[idx]) * (1.f - __expf(-ew)));
                }
            }
        }
    }
}

// ---------------------------------------------------------------------------
// Chunked WKV, pass A (parallel over b,h,chunk; 1 wave/block).
// ---------------------------------------------------------------------------
__global__ __launch_bounds__(64) void wkv_chunk_a(
    const ushort_t* __restrict__ ewB,
    ushort_t* rB, ushort_t* kB,
    const ushort_t* __restrict__ vB,
    ushort_t* __restrict__ uOut, float* __restrict__ dtot)
{
    const int c = blockIdx.x, h = blockIdx.y, b = blockIdx.z;
    const int lane = threadIdx.x;
    const int fr = lane & 15, quad = lane >> 4;
    __shared__ __align__(16) ushort_t kTT[64 * 40];
    __shared__ __align__(16) ushort_t vT [64 * 40];

    const size_t rowbase = ((size_t)b * Tdim + c * 32) * Cdim + h * 64;

    float Lrun = 0.f;                       // L_t for channel i=lane
    for (int t = 0; t < 32; ++t) {
        const size_t off = rowbase + (size_t)t * Cdim + lane;
        const float e  = b2f(ewB[off]);     // ew_t ; log d_t = -e
        const float rv = b2f(rB[off]);
        const float kv = b2f(kB[off]);
        const ushort_t rT = f2b(rv * __expf(Lrun));
        const ushort_t kT = f2b(kv * __expf(e - Lrun));   // e^{-L_{t+1}}
        rB[off] = rT;
        kB[off] = kT;
        kTT[lane * 40 + t] = kT;
        vT [lane * 40 + t] = vB[off];       // raw bf16 copy
        Lrun -= e;
    }
    const int slab = (b * 32 + h) * 64 + c;
    dtot[(size_t)slab * 64 + lane] = __expf(Lrun);
    __syncthreads();

    short8 af[4], bf[4];
#pragma unroll
    for (int mj = 0; mj < 4; ++mj)
        af[mj] = *(const short8*)&vT[(mj * 16 + fr) * 40 + quad * 8];
#pragma unroll
    for (int ni = 0; ni < 4; ++ni)
        bf[ni] = *(const short8*)&kTT[(ni * 16 + fr) * 40 + quad * 8];

    ushort_t* uo = uOut + (size_t)slab * 4096;
#pragma unroll
    for (int mj = 0; mj < 4; ++mj) {
#pragma unroll
        for (int ni = 0; ni < 4; ++ni) {
            f32x4 acc = {0.f, 0.f, 0.f, 0.f};
            acc = __builtin_amdgcn_mfma_f32_16x16x32_bf16(af[mj], bf[ni], acc, 0, 0, 0);
#pragma unroll
            for (int r = 0; r < 4; ++r) {
                const int j = mj * 16 + quad * 4 + r;   // C/D: row=quad*4+r
                const int i = ni * 16 + fr;             //      col=fr
                uo[j * 64 + i] = f2b(acc[r]);
            }
        }
    }
}

// ---------------------------------------------------------------------------
// Chunked WKV, pass B: per-scalar-thread chunk recurrence.
// ---------------------------------------------------------------------------
__global__ __launch_bounds__(256) void wkv_scan_b(
    ushort_t* __restrict__ slabs, const float* __restrict__ dtot,
    const float* __restrict__ s0)
{
    const int jhi = blockIdx.x, h = blockIdx.y, b = blockIdx.z;
    const int tid = threadIdx.x;
    const int ip = tid & 31, jl = tid >> 5;
    const int i0 = ip * 2;
    const int j  = jhi * 8 + jl;
    const size_t bh = (size_t)(b * 32 + h);
    const size_t base = bh * 64;                 // first slab of this (b,h)

    __shared__ float dsh[64 * 64];               // [c][i]
    for (int e = tid; e < 4096; e += 256) dsh[e] = dtot[base * 64 + e];

    const float* sp = s0 + bh * 4096;            // [i][j] fp32
    float sa = sp[i0 * 64 + j];
    float sb = sp[(i0 + 1) * 64 + j];
    __syncthreads();

    unsigned int* up =
        (unsigned int*)(slabs + base * 4096 + (size_t)j * 64 + i0);
#pragma unroll 8
    for (int c = 0; c < 64; ++c) {
        const unsigned int u = up[(size_t)c * 2048];
        const float2 dt = *(const float2*)&dsh[c * 64 + i0];
        const unsigned int pre =
            (unsigned int)f2b(sa) | ((unsigned int)f2b(sb) << 16);
        sa = dt.x * (sa + b2f((ushort_t)(u & 0xffffu)));
        sb = dt.y * (sb + b2f((ushort_t)(u >> 16)));
        up[(size_t)c * 2048] = pre;              // write PRE-chunk state
    }
}

// ---------------------------------------------------------------------------
// Chunked WKV, pass C (parallel over b,h,chunk; 1 wave/block).
// ---------------------------------------------------------------------------
__global__ __launch_bounds__(64) void wkv_chunk_c(
    const ushort_t* __restrict__ rB, const ushort_t* __restrict__ kB,
    ushort_t* vB, const ushort_t* __restrict__ slabs)
{
    const int c = blockIdx.x, h = blockIdx.y, b = blockIdx.z;
    const int lane = threadIdx.x;
    const int fr = lane & 15, quad = lane >> 4;
    __shared__ __align__(16) ushort_t rTs[32 * 64];   // [t][i^swz]
    __shared__ __align__(16) ushort_t kTs[32 * 64];   // [s][i^swz]
    __shared__ __align__(16) ushort_t vTs[64 * 40];   // [j][t], pad 40
    __shared__ __align__(16) ushort_t Ams[32 * 32];   // masked A, [t][s]

    const size_t rowbase = ((size_t)b * Tdim + c * 32) * Cdim + h * 64;

#pragma unroll
    for (int it = 0; it < 4; ++it) {
        const int idx = it * 64 + lane;           // 0..255
        const int t = idx >> 3, oct = idx & 7;
        const size_t g = rowbase + (size_t)t * Cdim + oct * 8;
        const int sw = ((oct ^ (t & 7)) * 8);
        *(short8*)&rTs[t * 64 + sw] = *(const short8*)&rB[g];
        *(short8*)&kTs[t * 64 + sw] = *(const short8*)&kB[g];
    }
    for (int t = 0; t < 32; ++t)
        vTs[lane * 40 + t] = vB[rowbase + (size_t)t * Cdim + lane];
    __syncthreads();

    f32x4 aacc[2][2];
#pragma unroll
    for (int mt = 0; mt < 2; ++mt)
#pragma unroll
        for (int st = 0; st < 2; ++st)
#pragma unroll
            for (int r = 0; r < 4; ++r) aacc[mt][st][r] = 0.f;

#pragma unroll
    for (int kk = 0; kk < 2; ++kk) {
        short8 ra[2], kb2[2];
#pragma unroll
        for (int mt = 0; mt < 2; ++mt) {
            const int t = mt * 16 + fr;
            ra[mt] = *(const short8*)&rTs[t * 64 + (((kk * 4 + quad) ^ (t & 7)) * 8)];
        }
#pragma unroll
        for (int st = 0; st < 2; ++st) {
            const int s = st * 16 + fr;
            kb2[st] = *(const short8*)&kTs[s * 64 + (((kk * 4 + quad) ^ (s & 7)) * 8)];
        }
#pragma unroll
        for (int mt = 0; mt < 2; ++mt)
#pragma unroll
            for (int st = 0; st < 2; ++st)
                aacc[mt][st] = __builtin_amdgcn_mfma_f32_16x16x32_bf16(
                    ra[mt], kb2[st], aacc[mt][st], 0, 0, 0);
    }

#pragma unroll
    for (int mt = 0; mt < 2; ++mt)
#pragma unroll
        for (int st = 0; st < 2; ++st)
#pragma unroll
            for (int r = 0; r < 4; ++r) {
                const int t = mt * 16 + quad * 4 + r;
                const int s = st * 16 + fr;
                Ams[t * 32 + s] = (t > s) ? f2b(aacc[mt][st][r]) : (ushort_t)0;
            }
    __syncthreads();

    f32x4 y[2][4];
#pragma unroll
    for (int mt = 0; mt < 2; ++mt)
#pragma unroll
        for (int nj = 0; nj < 4; ++nj)
#pragma unroll
            for (int r = 0; r < 4; ++r) y[mt][nj][r] = 0.f;

    {
        short8 aa[2], bb[4];
#pragma unroll
        for (int mt = 0; mt < 2; ++mt)
            aa[mt] = *(const short8*)&Ams[(mt * 16 + fr) * 32 + quad * 8];
#pragma unroll
        for (int nj = 0; nj < 4; ++nj)
            bb[nj] = *(const short8*)&vTs[(nj * 16 + fr) * 40 + quad * 8];
#pragma unroll
        for (int mt = 0; mt < 2; ++mt)
#pragma unroll
            for (int nj = 0; nj < 4; ++nj)
                y[mt][nj] = __builtin_amdgcn_mfma_f32_16x16x32_bf16(
                    aa[mt], bb[nj], y[mt][nj], 0, 0, 0);
    }
    const ushort_t* sl = slabs + (size_t)((b * 32 + h) * 64 + c) * 4096;
#pragma unroll
    for (int kk = 0; kk < 2; ++kk) {
        short8 aa[2], bb[4];
#pragma unroll
        for (int mt = 0; mt < 2; ++mt) {
            const int t = mt * 16 + fr;
            aa[mt] = *(const short8*)&rTs[t * 64 + (((kk * 4 + quad) ^ (t & 7)) * 8)];
        }
#pragma unroll
        for (int nj = 0; nj < 4; ++nj)
            bb[nj] = *(const short8*)&sl[(nj * 16 + fr) * 64 + kk * 32 + quad * 8];
#pragma unroll
        for (int mt = 0; mt < 2; ++mt)
#pragma unroll
            for (int nj = 0; nj < 4; ++nj)
                y[mt][nj] = __builtin_amdgcn_mfma_f32_16x16x32_bf16(
                    aa[mt], bb[nj], y[mt][nj], 0, 0, 0);
    }
#pragma unroll
    for (int mt = 0; mt < 2; ++mt)
#pragma unroll
        for (int nj = 0; nj < 4; ++nj)
#pragma unroll
            for (int r = 0; r < 4; ++r) {
                const int t = mt * 16 + quad * 4 + r;
                const int j = nj * 16 + fr;
                vB[rowbase + (size_t)t * Cdim + j] = f2b(y[mt][nj][r]);
            }
}

// ---------------------------------------------------------------------------
// LayerNorm over C of (y + v2) -> bf16
// ---------------------------------------------------------------------------
__global__ __launch_bounds__(256) void ln_k(
    const ushort_t* __restrict__ yB, const ushort_t* __restrict__ v2,
    const float* __restrict__ gamma, const float* __restrict__ beta,
    ushort_t* __restrict__ out)
{
    const size_t base = (size_t)blockIdx.x * Cdim;
    const int tid = threadIdx.x;
    const int wave = tid >> 6, lane = tid & 63;

    float sum = 0.f, sq = 0.f;
    for (int c = tid; c < Cdim; c += 256) {
        const float s = b2f(yB[base + c]) + b2f(v2[base + c]);
        sum += s; sq += s * s;
    }
#pragma unroll
    for (int o = 1; o < 64; o <<= 1) {
        sum += __shfl_xor(sum, o);
        sq  += __shfl_xor(sq, o);
    }
    __shared__ float red[8];
    if (lane == 0) { red[wave] = sum; red[4 + wave] = sq; }
    __syncthreads();
    sum = red[0] + red[1] + red[2] + red[3];
    sq  = red[4] + red[5] + red[6] + red[7];
    const float mu  = sum * (1.f / Cdim);
    const float var = sq * (1.f / Cdim) - mu * mu;
    const float rsd = rsqrtf(var + 1e-5f);
    for (int c = tid; c < Cdim; c += 256) {
        const float s = b2f(yB[base + c]) + b2f(v2[base + c]);
        out[base + c] = f2b((s - mu) * rsd * gamma[c] + beta[c]);
    }
}

// ---------------------------------------------------------------------------
extern "C" void kernel_launch(void* const* d_in, const int* in_sizes, int n_in,
                              void* d_out, int out_size, void* d_ws, size_t ws_size,
                              hipStream_t stream)
{
    (void)in_sizes; (void)n_in; (void)out_size; (void)ws_size;
    const float* x_in   = (const float*)d_in[0];
    const float* shiftS = (const float*)d_in[1];
    const float* wkvS   = (const float*)d_in[2];
    const float* maa_r  = (const float*)d_in[3];
    const float* maa_k  = (const float*)d_in[4];
    const float* maa_v  = (const float*)d_in[5];
    const float* maa_v2 = (const float*)d_in[6];
    const float* maa_w1 = (const float*)d_in[7];
    const float* maa_w2 = (const float*)d_in[8];
    const float* maa_w  = (const float*)d_in[9];
    const float* ww1    = (const float*)d_in[10];
    const float* ww2    = (const float*)d_in[11];
    const float* tdecay = (const float*)d_in[12];
    const float* dw1    = (const float*)d_in[13];
    const float* dw2    = (const float*)d_in[14];
    const float* recep  = (const float*)d_in[16];
    const float* tkey   = (const float*)d_in[17];
    const float* valw   = (const float*)d_in[18];
    const float* outw   = (const float*)d_in[19];
    const float* gamma  = (const float*)d_in[20];
    const float* beta   = (const float*)d_in[21];

    // ---- workspace layout (~183 MB) ----
    char* ws = (char*)d_ws;
    const size_t MB = 1ull << 20;
    ushort_t* xB    = (ushort_t*)(ws + 0 * MB);     // 32 MB  x (bf16); later ew
    ushort_t* mR    = (ushort_t*)(ws + 32 * MB);    // 32 MB  r -> rT -> y_ln
    ushort_t* mK    = (ushort_t*)(ws + 64 * MB);    // 32 MB  k -> kT
    ushort_t* mV2   = (ushort_t*)(ws + 96 * MB);    // 32 MB  v2
    ushort_t* xinB  = (ushort_t*)(ws + 128 * MB);   // 32 MB  x_in bf16; later mV/y
    ushort_t* mV    = xinB;                         //        (alias: xinB dead by then)
    ushort_t* valwB = (ushort_t*)(ws + 160 * MB);   // 8 MB
    ushort_t* outwB = (ushort_t*)(ws + 168 * MB);   // 8 MB
    char* sm = ws + 176 * MB;                       // small region (~7 MB)
    ushort_t* xxx   = (ushort_t*)(sm + 0);          // 8192x128 (2 MB); later dtot
    ushort_t* mwpre = (ushort_t*)(sm + 2097152);    // 8192x32  (512 KB)
    ushort_t* gbuf  = (ushort_t*)(sm + 2621440);    // 8192x128 (2 MB)
    ushort_t* w1T   = (ushort_t*)(sm + 4718592);    // 128x2048
    ushort_t* ww1T  = (ushort_t*)(sm + 5242880);    // 32x2048
    ushort_t* dw1T  = (ushort_t*)(sm + 5373952);    // 128x2048
    ushort_t* dw2T  = (ushort_t*)(sm + 5898240);    // 2048x128
    ushort_t* ww2T  = (ushort_t*)(sm + 6422528);    // 2048x32
    ushort_t* w2T   = (ushort_t*)(sm + 6553600);    // 4x 2048x32
    ushort_t* xwB   = (ushort_t*)d_out;             // xw scratch (dead later)
    ushort_t* ewB   = xB;                           // ew over xB (xB dead)
    ushort_t* slabs = (ushort_t*)d_out;             // 64 MB slabs in d_out
    float*    dtot  = (float*)xxx;                  // 2 MB exact (xxx dead)

    const dim3 blk(256);
    const float* NF = nullptr;
    ushort_t* NUM = nullptr;
    float* NFM = nullptr;

    // 0) fp32 -> bf16 conversions + weight transposes (one launch)
    prep_k<<<dim3(29184), blk, 0, stream>>>(x_in, valw, outw, xinB, valwB, outwB,
                                            maa_w1, ww1, dw1, dw2, ww2, maa_w2,
                                            w1T, ww1T, dw1T, dw2T, ww2T, w2T);
    // 1) x = x_in @ value_w^T (bf16) — 256² 8-phase
    gemm256_k<2><<<dim3(256), dim3(512), 0, stream>>>(xinB, valwB, xB, NFM);
    // 2+3) xxx = tanh(x_in @ maa_w1); mwpre = tanh(x @ maa_w_w1) — concurrent
    tanh2_k<<<dim3(64, 2), blk, 0, stream>>>(xinB, w1T, xB, ww1T, xxx, mwpre);
    // 4) all five K=32 mix GEMMs + token-shift epilogues, fused
    mix5_k<<<dim3(64, 16), blk, 0, stream>>>(xxx, mwpre, w2T, ww2T, xB, shiftS,
                                             maa_r, maa_k, maa_v, maa_v2, maa_w,
                                             recep, tkey, mR, mK, mV, mV2, xwB);
    // 5) g = tanh(xw @ decay_w1)
    gemm_bt_k<1><<<dim3(64, 1), blk, 0, stream>>>(xwB, 2048, dw1T, 2048, 128, 2048,
                                                  gbuf, 128, NF, NUM);
    // 6) ew = exp(time_decay + g @ decay_w2) -> ewB; k *= (1 - exp(-ew))
    gemm_bt_k<3><<<dim3(64, 16), blk, 0, stream>>>(gbuf, 128, dw2T, 128, 2048, 128,
                                                   ewB, 2048, tdecay, mK);
    // 7) chunked wkv
    wkv_chunk_a<<<dim3(64, 32, 4), dim3(64), 0, stream>>>(ewB, mR, mK, mV, slabs, dtot);
    wkv_scan_b<<<dim3(8, 32, 4),   blk,      0, stream>>>(slabs, dtot, wkvS);
    wkv_chunk_c<<<dim3(64, 32, 4), dim3(64), 0, stream>>>(mR, mK, mV, slabs);
    // 8) LayerNorm(y + v2) -> y_ln (reuses mR)
    ln_k<<<dim3(8192), blk, 0, stream>>>(mV, mV2, gamma, beta, mR);
    // 9) out = y_ln @ output_w^T -> d_out as FP32 — 256² 8-phase
    gemm256_k<5><<<dim3(256), dim3(512), 0, stream>>>(mR, outwB, NUM, (float*)d_out);
}

// Round 7
// 647.833 us; speedup vs baseline: 1.1560x; 1.1560x over previous
//
#include <hip/hip_runtime.h>

// ---------------------------------------------------------------------------
// RWKV6 Tmix (B=4,T=2048,C=2048,H=32,HS=64). Inputs fp32, OUTPUT FP32.
// Round 6: chunked linear-attention wkv. Round 7: parallel chunk recurrence.
// Round 8/9: 256x256-tile 8-phase GEMM for the two K=2048 GEMMs.
// Round 10: mix5_k fusion + prep_k merge. Round 11: tanh2_k merge (KEPT);
// LDS-outstage epilogue (REVERTED in round 12 — it cut occupancy 3->2
// blocks/CU and serialized waves: 93 -> 190us. Round-10 epilogue restored.)
// ---------------------------------------------------------------------------

#define Cdim 2048
#define Tdim 2048

using short8 = __attribute__((ext_vector_type(8))) short;   // 8 x bf16
using f32x4  = __attribute__((ext_vector_type(4))) float;
using us4    = __attribute__((ext_vector_type(4))) unsigned short;
typedef unsigned short ushort_t;

__device__ __forceinline__ float b2f(unsigned short h) {
    union { unsigned int u; float f; } x; x.u = ((unsigned int)h) << 16; return x.f;
}
__device__ __forceinline__ unsigned short f2b(float f) {
    union { float f; unsigned int u; } x; x.f = f;
    unsigned int r = x.u + 0x7fffu + ((x.u >> 16) & 1u);   // RNE
    return (unsigned short)(r >> 16);
}

__device__ __forceinline__ void gload16(const void* g, void* l) {
    __builtin_amdgcn_global_load_lds(
        (__attribute__((address_space(1))) void*)g,
        (__attribute__((address_space(3))) void*)l, 16, 0, 0);
}

// ---------------------------------------------------------------------------
// prep_k: fp32->bf16 convert (x_in, value_w, output_w) + all weight
// transposes (fp32 -> bf16 transposed), one launch.
// ---------------------------------------------------------------------------
__global__ __launch_bounds__(256) void prep_k(
    const float* __restrict__ x_in, const float* __restrict__ valw,
    const float* __restrict__ outw,
    ushort_t* __restrict__ xinB, ushort_t* __restrict__ valwB,
    ushort_t* __restrict__ outwB,
    const float* __restrict__ w1,  const float* __restrict__ ww1,
    const float* __restrict__ dw1, const float* __restrict__ dw2,
    const float* __restrict__ ww2, const float* __restrict__ w2,
    ushort_t* __restrict__ w1T,  ushort_t* __restrict__ ww1T,
    ushort_t* __restrict__ dw1T, ushort_t* __restrict__ dw2T,
    ushort_t* __restrict__ ww2T, ushort_t* __restrict__ w2T)
{
    size_t g = (size_t)blockIdx.x * 256 + threadIdx.x;
    if (g < 6291456) {
        const float* src; ushort_t* dst; size_t e;
        if (g < 4194304)      { src = x_in; dst = xinB;  e = g; }
        else if (g < 5242880) { src = valw; dst = valwB; e = g - 4194304; }
        else                  { src = outw; dst = outwB; e = g - 5242880; }
        const float4 v = ((const float4*)src)[e];
        us4 o; o.x = f2b(v.x); o.y = f2b(v.y); o.z = f2b(v.z); o.w = f2b(v.w);
        ((us4*)dst)[e] = o;
        return;
    }
    int idx = (int)(g - 6291456);
    if (idx < 262144) { int r = idx >> 7, c = idx & 127; w1T[c * 2048 + r] = f2b(w1[idx]); return; }
    idx -= 262144;
    if (idx < 65536)  { int r = idx >> 5, c = idx & 31;  ww1T[c * 2048 + r] = f2b(ww1[idx]); return; }
    idx -= 65536;
    if (idx < 262144) { int r = idx >> 7, c = idx & 127; dw1T[c * 2048 + r] = f2b(dw1[idx]); return; }
    idx -= 262144;
    if (idx < 262144) { int r = idx >> 11, c = idx & 2047; dw2T[c * 128 + r] = f2b(dw2[idx]); return; }
    idx -= 262144;
    if (idx < 65536)  { int r = idx >> 11, c = idx & 2047; ww2T[c * 32 + r] = f2b(ww2[idx]); return; }
    idx -= 65536;
    { int f = idx >> 16, rem = idx & 65535; int r = rem >> 11, c = rem & 2047;
      w2T[f * 65536 + c * 32 + r] = f2b(w2[idx]); }
}

// ---------------------------------------------------------------------------
// 256x256-tile 8-phase GEMM, M=8192 N=2048 K=2048, C = A @ B^T (both bf16
// row-major, ld=2048). MODE 2: bf16 store; MODE 5: fp32 store. (round 8/9)
// ---------------------------------------------------------------------------
template <int MODE>
__global__ __launch_bounds__(512, 2) void gemm256_k(
    const ushort_t* __restrict__ A,
    const ushort_t* __restrict__ Bw,
    ushort_t* __restrict__ outB,
    float* __restrict__ outF)
{
    __shared__ __align__(16) ushort_t lds[65536];   // A: [0,32768) B: [32768,65536)

    const int tid  = threadIdx.x;
    const int wave = tid >> 6, lane = tid & 63;
    const int wm = wave >> 2, wn = wave & 3;        // 2M x 4N wave grid
    const int fr = lane & 15, quad = lane >> 4;
    const int og8 = (((lane & 7) ^ ((lane >> 3) & 7)) * 8);

    const int id  = blockIdx.x;
    const int swz = (id & 7) * 32 + (id >> 3);
    const int mbase = (swz >> 3) * 256;             // 32 m-tiles
    const int nbase = (swz & 7) * 256;              // 8 n-tiles

    f32x4 acc[8][4];
#pragma unroll
    for (int i = 0; i < 8; ++i)
#pragma unroll
        for (int j = 0; j < 4; ++j)
#pragma unroll
            for (int r = 0; r < 4; ++r) acc[i][j][r] = 0.f;

    auto stage_half = [&](const ushort_t* __restrict__ G, int growb,
                          int dstb, int kt) {
#pragma unroll
        for (int i = 0; i < 2; ++i) {
            const int rh = i * 64 + wave * 8 + (lane >> 3);
            gload16(G + (size_t)(growb + rh) * Cdim + kt * 64 + og8,
                    &lds[dstb + (i * 512 + wave * 64) * 8]);
        }
    };

    short8 afr[4][2], bfr[2][2];

    auto LOADA = [&](int p, int mo) {
#pragma unroll
        for (int mi = 0; mi < 4; ++mi)
#pragma unroll
            for (int k = 0; k < 2; ++k) {
                const int row = wm * 128 + (mo + mi) * 16 + fr;
                afr[mi][k] = *(const short8*)
                    &lds[p + row * 64 + (((k * 4 + quad) ^ (fr & 7)) * 8)];
            }
    };
    auto LOADB = [&](int p, int no) {
#pragma unroll
        for (int ni = 0; ni < 2; ++ni)
#pragma unroll
            for (int k = 0; k < 2; ++k) {
                const int row = wn * 64 + (no + ni) * 16 + fr;
                bfr[ni][k] = *(const short8*)
                    &lds[32768 + p + row * 64 + (((k * 4 + quad) ^ (fr & 7)) * 8)];
            }
    };
    auto MFMA16 = [&](int mo, int no) {
        __builtin_amdgcn_s_setprio(1);
#pragma unroll
        for (int mi = 0; mi < 4; ++mi)
#pragma unroll
            for (int ni = 0; ni < 2; ++ni)
#pragma unroll
                for (int k = 0; k < 2; ++k)
                    acc[mo + mi][no + ni] = __builtin_amdgcn_mfma_f32_16x16x32_bf16(
                        afr[mi][k], bfr[ni][k], acc[mo + mi][no + ni], 0, 0, 0);
        __builtin_amdgcn_s_setprio(0);
    };

    // prologue: tile 0 -> buf 0
    stage_half(A,  mbase,       0,            0);
    stage_half(A,  mbase + 128, 8192,         0);
    stage_half(Bw, nbase,       32768,        0);
    stage_half(Bw, nbase + 128, 32768 + 8192, 0);

#pragma unroll 2
    for (int t = 0; t < 32; ++t) {
        const int p  = (t & 1) * 16384;      // compute buffer (element offset)
        const int q  = 16384 - p;            // stage buffer
        const int kn = (t < 31) ? t + 1 : t; // clamped prefetch tile

        // ---- P1: m[0..3] x n[0..1]; stage A(t+1) ----
        asm volatile("s_waitcnt vmcnt(0)\n\ts_barrier" ::: "memory");
        LOADA(p, 0); LOADB(p, 0);
        stage_half(A, mbase,       q,        kn);
        stage_half(A, mbase + 128, q + 8192, kn);
        asm volatile("s_barrier" ::: "memory");
        asm volatile("s_waitcnt lgkmcnt(0)" ::: "memory");
        MFMA16(0, 0);

        // ---- P2: m[0..3] x n[2..3]; stage B(t+1) ----
        asm volatile("s_barrier" ::: "memory");
        LOADB(p, 2);
        stage_half(Bw, nbase,       32768 + q,        kn);
        stage_half(Bw, nbase + 128, 32768 + q + 8192, kn);
        asm volatile("s_barrier" ::: "memory");
        asm volatile("s_waitcnt lgkmcnt(0)" ::: "memory");
        MFMA16(0, 2);

        // ---- P3: m[4..7] x n[2..3] ----
        asm volatile("s_barrier" ::: "memory");
        LOADA(p, 4);
        asm volatile("s_barrier" ::: "memory");
        asm volatile("s_waitcnt lgkmcnt(0)" ::: "memory");
        MFMA16(4, 2);

        // ---- P4: m[4..7] x n[0..1] ----
        asm volatile("s_barrier" ::: "memory");
        LOADB(p, 0);
        asm volatile("s_barrier" ::: "memory");
        asm volatile("s_waitcnt lgkmcnt(0)" ::: "memory");
        MFMA16(4, 0);
    }

    const int row0 = mbase + wm * 128 + quad * 4;
    const int col0 = nbase + wn * 64 + fr;
#pragma unroll
    for (int mi = 0; mi < 8; ++mi)
#pragma unroll
        for (int ni = 0; ni < 4; ++ni)
#pragma unroll
            for (int r = 0; r < 4; ++r) {
                const int row = row0 + mi * 16 + r;
                const int col = col0 + ni * 16;
                const size_t idx = (size_t)row * Cdim + col;
                if constexpr (MODE == 2) outB[idx] = f2b(acc[mi][ni][r]);
                else                     outF[idx] = acc[mi][ni][r];
            }
}

// ---------------------------------------------------------------------------
// mix5_k (round-10 body, restored): five K=32 token-shift mix GEMMs fused.
// Block = 128x128 output tile, 4 waves. x tile (+ shifted row) staged in LDS
// once; per output o: {A,B 128x32 staged via gload_lds w/ source-XOR octet
// swizzle, 16 MFMA, epilogue val = x+(xp-x)*(cvec+acc) [*cmul] -> outs[o]}.
// LDS ~51KB -> 3 blocks/CU.
// ---------------------------------------------------------------------------
__global__ __launch_bounds__(256) void mix5_k(
    const ushort_t* __restrict__ xxx,   // [8192][128] bf16
    const ushort_t* __restrict__ mwpre, // [8192][32]  bf16
    const ushort_t* __restrict__ w2T,   // 4x [2048][32] bf16
    const ushort_t* __restrict__ ww2T,  // [2048][32] bf16
    const ushort_t* __restrict__ xB,    // [8192][2048] bf16
    const float*    __restrict__ shiftS,// [4][2048] fp32
    const float* __restrict__ maa_r, const float* __restrict__ maa_k,
    const float* __restrict__ maa_v, const float* __restrict__ maa_v2,
    const float* __restrict__ maa_w,
    const float* __restrict__ recep, const float* __restrict__ tkey,
    ushort_t* __restrict__ mR,  ushort_t* __restrict__ mK,
    ushort_t* __restrict__ mV,  ushort_t* __restrict__ mV2,
    ushort_t* __restrict__ xwB)
{
    __shared__ __align__(16) ushort_t xs[129 * 136];   // [1+row][col], pad 136
    __shared__ __align__(16) ushort_t abuf[128 * 32];
    __shared__ __align__(16) ushort_t bbuf[128 * 32];

    const int tid  = threadIdx.x;
    const int wave = tid >> 6, lane = tid & 63;
    const int wm = wave >> 1, wn = wave & 1;
    const int fr = lane & 15, quad = lane >> 4;

    const int mbase = blockIdx.x * 128;
    const int nbase = blockIdx.y * 128;
    const int b  = mbase >> 11;          // batch
    const int t0 = mbase & 2047;         // first t of tile

    // ---- stage x tile: xs[1+r][c] = xB[mbase+r][nbase+c], 16B granules ----
#pragma unroll
    for (int it = 0; it < 8; ++it) {
        const int idx = it * 256 + tid;          // [0,2048)
        const int r = idx >> 4, c8 = (idx & 15) * 8;
        *(short8*)&xs[(r + 1) * 136 + c8] =
            *(const short8*)&xB[(size_t)(mbase + r) * Cdim + nbase + c8];
    }
    // shifted row (xp for local row 0): fp32 shiftS handled in epilogue
    if (tid < 128)
        xs[tid] = (t0 > 0) ? xB[(size_t)(mbase - 1) * Cdim + nbase + tid]
                           : f2b(shiftS[(size_t)b * Cdim + nbase + tid]);

    // per-output sources
    const ushort_t* asrc[5] = {xxx, xxx + 32, xxx + 64, xxx + 96, mwpre};
    const int       alda[5] = {128, 128, 128, 128, 32};
    const ushort_t* bsrc[5] = {w2T, w2T + 65536, w2T + 131072, w2T + 196608, ww2T};
    const float*    cvec[5] = {maa_r, maa_k, maa_v, maa_v2, maa_w};
    const float*    cmul[5] = {recep, tkey, nullptr, nullptr, nullptr};
    ushort_t*       outs[5] = {mR, mK, mV, mV2, xwB};

    // stage A_o/B_o 128x32 tiles: linear LDS dest, source octet pre-swizzled
    // (physical oct = logical oct ^ (row&3)) so ds_read spreads banks.
    auto stageAB = [&](int o) {
#pragma unroll
        for (int i = 0; i < 2; ++i) {
            const int slot = i * 256 + tid;      // [0,512)
            const int r = slot >> 2, oct = slot & 3;
            const int sw = ((oct ^ (r & 3)) * 8);
            gload16(asrc[o] + (size_t)(mbase + r) * alda[o] + sw, &abuf[slot * 8]);
            gload16(bsrc[o] + (size_t)(nbase + r) * 32 + sw,      &bbuf[slot * 8]);
        }
    };

    stageAB(0);
    __syncthreads();    // drains vmcnt (stages) + lgkmcnt (xs ds_writes)

    const int row0l = wm * 64 + quad * 4;
    const int col0l = wn * 64 + fr;

#pragma unroll
    for (int o = 0; o < 5; ++o) {
        // ---- fragments from abuf/bbuf ----
        short8 af[4], bf[4];
#pragma unroll
        for (int mi = 0; mi < 4; ++mi) {
            const int r = wm * 64 + mi * 16 + fr;
            af[mi] = *(const short8*)&abuf[r * 32 + ((quad ^ (r & 3)) * 8)];
        }
#pragma unroll
        for (int ni = 0; ni < 4; ++ni) {
            const int r = wn * 64 + ni * 16 + fr;
            bf[ni] = *(const short8*)&bbuf[r * 32 + ((quad ^ (r & 3)) * 8)];
        }
        asm volatile("s_waitcnt lgkmcnt(0)" ::: "memory");
        __builtin_amdgcn_sched_barrier(0);
        asm volatile("s_barrier" ::: "memory");   // all waves done reading bufs
        if (o < 4) stageAB(o + 1);                // overwrite bufs for next o

        f32x4 acc[4][4];
#pragma unroll
        for (int mi = 0; mi < 4; ++mi)
#pragma unroll
            for (int ni = 0; ni < 4; ++ni) {
#pragma unroll
                for (int r = 0; r < 4; ++r) acc[mi][ni][r] = 0.f;
                acc[mi][ni] = __builtin_amdgcn_mfma_f32_16x16x32_bf16(
                    af[mi], bf[ni], acc[mi][ni], 0, 0, 0);
            }

        // ---- epilogue: val = x + (xp-x)*(cvec+acc) [*cmul] ----
        const float* cv = cvec[o];
        const float* cm = cmul[o];
        ushort_t* op = outs[o];
#pragma unroll
        for (int mi = 0; mi < 4; ++mi)
#pragma unroll
            for (int ni = 0; ni < 4; ++ni)
#pragma unroll
                for (int r = 0; r < 4; ++r) {
                    const int lr = row0l + mi * 16 + r;
                    const int lc = col0l + ni * 16;
                    const int col = nbase + lc;
                    const float x  = b2f(xs[(lr + 1) * 136 + lc]);
                    const float xp = (lr == 0 && t0 == 0)
                                         ? shiftS[(size_t)b * Cdim + col]
                                         : b2f(xs[lr * 136 + lc]);
                    float val = x + (xp - x) * (cv[col] + acc[mi][ni][r]);
                    if (cm) val *= cm[col];
                    op[(size_t)(mbase + lr) * Cdim + col] = f2b(val);
                }
        if (o < 4)
            asm volatile("s_waitcnt vmcnt(0)\n\ts_barrier" ::: "memory");
    }
}

// ---------------------------------------------------------------------------
// tanh2_k: the two skinny tanh GEMMs in one launch, grid (64,2). (round 11)
// by=0: xxx  = tanh(x_in @ maa_w1)   N=128, ldc=128
// by=1: mwpre= tanh(x    @ maa_w_w1) N=32,  ldc=32
// ---------------------------------------------------------------------------
__global__ __launch_bounds__(256) void tanh2_k(
    const ushort_t* __restrict__ xinB, const ushort_t* __restrict__ w1T,
    const ushort_t* __restrict__ xB,   const ushort_t* __restrict__ ww1T,
    ushort_t* __restrict__ xxx, ushort_t* __restrict__ mwpre)
{
    const int by = blockIdx.y;
    const ushort_t* A  = by ? xB    : xinB;
    const ushort_t* Bw = by ? ww1T  : w1T;
    ushort_t* out      = by ? mwpre : xxx;
    const int N        = by ? 32 : 128;
    const int ldc      = N;

    __shared__ __align__(16) ushort_t At[128 * 32];
    __shared__ __align__(16) ushort_t Bt[128 * 32];

    const int tid  = threadIdx.x;
    const int wave = tid >> 6, lane = tid & 63;
    const int wm = wave >> 1, wn = wave & 1;
    const int fr = lane & 15, quad = lane >> 4;
    const int cr = lane >> 2;
    const int cc = (lane & 3) * 8;

    f32x4 acc[4][4];
#pragma unroll
    for (int i = 0; i < 4; ++i)
#pragma unroll
        for (int j = 0; j < 4; ++j)
#pragma unroll
            for (int r = 0; r < 4; ++r) acc[i][j][r] = 0.f;

    const int mbase = blockIdx.x * 128;

    for (int k0 = 0; k0 < 2048; k0 += 32) {
        __syncthreads();
#pragma unroll
        for (int c2 = 0; c2 < 2; ++c2) {
            const int q  = wave * 2 + c2;
            const int ar = mbase + q * 16 + cr;
            gload16(A + (size_t)ar * 2048 + k0 + cc, &At[q * 512]);
            int br = q * 16 + cr;
            br = br < N ? br : N - 1;   // clamp for skinny-N
            gload16(Bw + (size_t)br * 2048 + k0 + cc, &Bt[q * 512]);
        }
        __syncthreads();

        short8 af[4], bfr[4];
#pragma unroll
        for (int mi = 0; mi < 4; ++mi)
            af[mi] = *(const short8*)&At[(wm * 64 + mi * 16 + fr) * 32 + quad * 8];
#pragma unroll
        for (int ni = 0; ni < 4; ++ni)
            bfr[ni] = *(const short8*)&Bt[(wn * 64 + ni * 16 + fr) * 32 + quad * 8];
#pragma unroll
        for (int mi = 0; mi < 4; ++mi)
#pragma unroll
            for (int ni = 0; ni < 4; ++ni)
                acc[mi][ni] = __builtin_amdgcn_mfma_f32_16x16x32_bf16(
                    af[mi], bfr[ni], acc[mi][ni], 0, 0, 0);
    }

    const int row0 = mbase + wm * 64 + quad * 4;
    const int col0 = wn * 64 + fr;
#pragma unroll
    for (int mi = 0; mi < 4; ++mi)
#pragma unroll
        for (int ni = 0; ni < 4; ++ni) {
            const int col = col0 + ni * 16;
#pragma unroll
            for (int r = 0; r < 4; ++r) {
                const int row = row0 + mi * 16 + r;
                if (col < N)
                    out[(size_t)row * ldc + col] = f2b(tanhf(acc[mi][ni][r]));
            }
        }
}

// ---------------------------------------------------------------------------
// BT GEMM (128-tile): MODE 1: tanh (guarded); MODE 3: decay fuse.
// ---------------------------------------------------------------------------
template <int MODE>
__global__ __launch_bounds__(256) void gemm_bt_k(
    const ushort_t* __restrict__ A, int lda,
    const ushort_t* __restrict__ Bw, int ldb,
    int N, int K,
    ushort_t* __restrict__ outB, int ldc,
    const float* __restrict__ cvec,
    ushort_t* __restrict__ inplace)
{
    __shared__ __align__(16) ushort_t At[128 * 32];
    __shared__ __align__(16) ushort_t Bt[128 * 32];

    const int tid  = threadIdx.x;
    const int wave = tid >> 6, lane = tid & 63;
    const int wm = wave >> 1, wn = wave & 1;
    const int fr = lane & 15, quad = lane >> 4;
    const int cr = lane >> 2;
    const int cc = (lane & 3) * 8;

    f32x4 acc[4][4];
#pragma unroll
    for (int i = 0; i < 4; ++i)
#pragma unroll
        for (int j = 0; j < 4; ++j)
#pragma unroll
            for (int r = 0; r < 4; ++r) acc[i][j][r] = 0.f;

    const int mbase = blockIdx.x * 128;
    const int nbase = blockIdx.y * 128;

    for (int k0 = 0; k0 < K; k0 += 32) {
        __syncthreads();
#pragma unroll
        for (int c2 = 0; c2 < 2; ++c2) {
            const int q  = wave * 2 + c2;
            const int ar = mbase + q * 16 + cr;
            gload16(A + (size_t)ar * lda + k0 + cc, &At[q * 512]);
            int br = nbase + q * 16 + cr;
            br = br < N ? br : N - 1;
            gload16(Bw + (size_t)br * ldb + k0 + cc, &Bt[q * 512]);
        }
        __syncthreads();

        short8 af[4], bfr[4];
#pragma unroll
        for (int mi = 0; mi < 4; ++mi)
            af[mi] = *(const short8*)&At[(wm * 64 + mi * 16 + fr) * 32 + quad * 8];
#pragma unroll
        for (int ni = 0; ni < 4; ++ni)
            bfr[ni] = *(const short8*)&Bt[(wn * 64 + ni * 16 + fr) * 32 + quad * 8];
#pragma unroll
        for (int mi = 0; mi < 4; ++mi)
#pragma unroll
            for (int ni = 0; ni < 4; ++ni)
                acc[mi][ni] = __builtin_amdgcn_mfma_f32_16x16x32_bf16(
                    af[mi], bfr[ni], acc[mi][ni], 0, 0, 0);
    }

    const int row0 = mbase + wm * 64 + quad * 4;
    const int col0 = nbase + wn * 64 + fr;
#pragma unroll
    for (int mi = 0; mi < 4; ++mi) {
#pragma unroll
        for (int ni = 0; ni < 4; ++ni) {
            const int col = col0 + ni * 16;
#pragma unroll
            for (int r = 0; r < 4; ++r) {
                const int row = row0 + mi * 16 + r;
                const float v = acc[mi][ni][r];
                const size_t idx = (size_t)row * ldc + col;
                if constexpr (MODE == 1) {
                    if (col < N) outB[idx] = f2b(tanhf(v));
                } else {  // MODE 3
                    const float w  = cvec[col] + v;
                    const float ew = __expf(w);
                    outB[idx] = f2b(ew);
                    inplace[idx] = f2b(b2f(inplace[idx]) * (1.f - __expf(-ew)));
                }
            }
        }
    }
}

// ---------------------------------------------------------------------------
// Chunked WKV, pass A (parallel over b,h,chunk; 1 wave/block).
// ---------------------------------------------------------------------------
__global__ __launch_bounds__(64) void wkv_chunk_a(
    const ushort_t* __restrict__ ewB,
    ushort_t* rB, ushort_t* kB,
    const ushort_t* __restrict__ vB,
    ushort_t* __restrict__ uOut, float* __restrict__ dtot)
{
    const int c = blockIdx.x, h = blockIdx.y, b = blockIdx.z;
    const int lane = threadIdx.x;
    const int fr = lane & 15, quad = lane >> 4;
    __shared__ __align__(16) ushort_t kTT[64 * 40];
    __shared__ __align__(16) ushort_t vT [64 * 40];

    const size_t rowbase = ((size_t)b * Tdim + c * 32) * Cdim + h * 64;

    float Lrun = 0.f;                       // L_t for channel i=lane
    for (int t = 0; t < 32; ++t) {
        const size_t off = rowbase + (size_t)t * Cdim + lane;
        const float e  = b2f(ewB[off]);     // ew_t ; log d_t = -e
        const float rv = b2f(rB[off]);
        const float kv = b2f(kB[off]);
        const ushort_t rT = f2b(rv * __expf(Lrun));
        const ushort_t kT = f2b(kv * __expf(e - Lrun));   // e^{-L_{t+1}}
        rB[off] = rT;
        kB[off] = kT;
        kTT[lane * 40 + t] = kT;
        vT [lane * 40 + t] = vB[off];       // raw bf16 copy
        Lrun -= e;
    }
    const int slab = (b * 32 + h) * 64 + c;
    dtot[(size_t)slab * 64 + lane] = __expf(Lrun);
    __syncthreads();

    short8 af[4], bf[4];
#pragma unroll
    for (int mj = 0; mj < 4; ++mj)
        af[mj] = *(const short8*)&vT[(mj * 16 + fr) * 40 + quad * 8];
#pragma unroll
    for (int ni = 0; ni < 4; ++ni)
        bf[ni] = *(const short8*)&kTT[(ni * 16 + fr) * 40 + quad * 8];

    ushort_t* uo = uOut + (size_t)slab * 4096;
#pragma unroll
    for (int mj = 0; mj < 4; ++mj) {
#pragma unroll
        for (int ni = 0; ni < 4; ++ni) {
            f32x4 acc = {0.f, 0.f, 0.f, 0.f};
            acc = __builtin_amdgcn_mfma_f32_16x16x32_bf16(af[mj], bf[ni], acc, 0, 0, 0);
#pragma unroll
            for (int r = 0; r < 4; ++r) {
                const int j = mj * 16 + quad * 4 + r;   // C/D: row=quad*4+r
                const int i = ni * 16 + fr;             //      col=fr
                uo[j * 64 + i] = f2b(acc[r]);
            }
        }
    }
}

// ---------------------------------------------------------------------------
// Chunked WKV, pass B: per-scalar-thread chunk recurrence.
// ---------------------------------------------------------------------------
__global__ __launch_bounds__(256) void wkv_scan_b(
    ushort_t* __restrict__ slabs, const float* __restrict__ dtot,
    const float* __restrict__ s0)
{
    const int jhi = blockIdx.x, h = blockIdx.y, b = blockIdx.z;
    const int tid = threadIdx.x;
    const int ip = tid & 31, jl = tid >> 5;
    const int i0 = ip * 2;
    const int j  = jhi * 8 + jl;
    const size_t bh = (size_t)(b * 32 + h);
    const size_t base = bh * 64;                 // first slab of this (b,h)

    __shared__ float dsh[64 * 64];               // [c][i]
    for (int e = tid; e < 4096; e += 256) dsh[e] = dtot[base * 64 + e];

    const float* sp = s0 + bh * 4096;            // [i][j] fp32
    float sa = sp[i0 * 64 + j];
    float sb = sp[(i0 + 1) * 64 + j];
    __syncthreads();

    unsigned int* up =
        (unsigned int*)(slabs + base * 4096 + (size_t)j * 64 + i0);
#pragma unroll 8
    for (int c = 0; c < 64; ++c) {
        const unsigned int u = up[(size_t)c * 2048];
        const float2 dt = *(const float2*)&dsh[c * 64 + i0];
        const unsigned int pre =
            (unsigned int)f2b(sa) | ((unsigned int)f2b(sb) << 16);
        sa = dt.x * (sa + b2f((ushort_t)(u & 0xffffu)));
        sb = dt.y * (sb + b2f((ushort_t)(u >> 16)));
        up[(size_t)c * 2048] = pre;              // write PRE-chunk state
    }
}

// ---------------------------------------------------------------------------
// Chunked WKV, pass C (parallel over b,h,chunk; 1 wave/block).
// ---------------------------------------------------------------------------
__global__ __launch_bounds__(64) void wkv_chunk_c(
    const ushort_t* __restrict__ rB, const ushort_t* __restrict__ kB,
    ushort_t* vB, const ushort_t* __restrict__ slabs)
{
    const int c = blockIdx.x, h = blockIdx.y, b = blockIdx.z;
    const int lane = threadIdx.x;
    const int fr = lane & 15, quad = lane >> 4;
    __shared__ __align__(16) ushort_t rTs[32 * 64];   // [t][i^swz]
    __shared__ __align__(16) ushort_t kTs[32 * 64];   // [s][i^swz]
    __shared__ __align__(16) ushort_t vTs[64 * 40];   // [j][t], pad 40
    __shared__ __align__(16) ushort_t Ams[32 * 32];   // masked A, [t][s]

    const size_t rowbase = ((size_t)b * Tdim + c * 32) * Cdim + h * 64;

#pragma unroll
    for (int it = 0; it < 4; ++it) {
        const int idx = it * 64 + lane;           // 0..255
        const int t = idx >> 3, oct = idx & 7;
        const size_t g = rowbase + (size_t)t * Cdim + oct * 8;
        const int sw = ((oct ^ (t & 7)) * 8);
        *(short8*)&rTs[t * 64 + sw] = *(const short8*)&rB[g];
        *(short8*)&kTs[t * 64 + sw] = *(const short8*)&kB[g];
    }
    for (int t = 0; t < 32; ++t)
        vTs[lane * 40 + t] = vB[rowbase + (size_t)t * Cdim + lane];
    __syncthreads();

    f32x4 aacc[2][2];
#pragma unroll
    for (int mt = 0; mt < 2; ++mt)
#pragma unroll
        for (int st = 0; st < 2; ++st)
#pragma unroll
            for (int r = 0; r < 4; ++r) aacc[mt][st][r] = 0.f;

#pragma unroll
    for (int kk = 0; kk < 2; ++kk) {
        short8 ra[2], kb2[2];
#pragma unroll
        for (int mt = 0; mt < 2; ++mt) {
            const int t = mt * 16 + fr;
            ra[mt] = *(const short8*)&rTs[t * 64 + (((kk * 4 + quad) ^ (t & 7)) * 8)];
        }
#pragma unroll
        for (int st = 0; st < 2; ++st) {
            const int s = st * 16 + fr;
            kb2[st] = *(const short8*)&kTs[s * 64 + (((kk * 4 + quad) ^ (s & 7)) * 8)];
        }
#pragma unroll
        for (int mt = 0; mt < 2; ++mt)
#pragma unroll
            for (int st = 0; st < 2; ++st)
                aacc[mt][st] = __builtin_amdgcn_mfma_f32_16x16x32_bf16(
                    ra[mt], kb2[st], aacc[mt][st], 0, 0, 0);
    }

#pragma unroll
    for (int mt = 0; mt < 2; ++mt)
#pragma unroll
        for (int st = 0; st < 2; ++st)
#pragma unroll
            for (int r = 0; r < 4; ++r) {
                const int t = mt * 16 + quad * 4 + r;
                const int s = st * 16 + fr;
                Ams[t * 32 + s] = (t > s) ? f2b(aacc[mt][st][r]) : (ushort_t)0;
            }
    __syncthreads();

    f32x4 y[2][4];
#pragma unroll
    for (int mt = 0; mt < 2; ++mt)
#pragma unroll
        for (int nj = 0; nj < 4; ++nj)
#pragma unroll
            for (int r = 0; r < 4; ++r) y[mt][nj][r] = 0.f;

    {
        short8 aa[2], bb[4];
#pragma unroll
        for (int mt = 0; mt < 2; ++mt)
            aa[mt] = *(const short8*)&Ams[(mt * 16 + fr) * 32 + quad * 8];
#pragma unroll
        for (int nj = 0; nj < 4; ++nj)
            bb[nj] = *(const short8*)&vTs[(nj * 16 + fr) * 40 + quad * 8];
#pragma unroll
        for (int mt = 0; mt < 2; ++mt)
#pragma unroll
            for (int nj = 0; nj < 4; ++nj)
                y[mt][nj] = __builtin_amdgcn_mfma_f32_16x16x32_bf16(
                    aa[mt], bb[nj], y[mt][nj], 0, 0, 0);
    }
    const ushort_t* sl = slabs + (size_t)((b * 32 + h) * 64 + c) * 4096;
#pragma unroll
    for (int kk = 0; kk < 2; ++kk) {
        short8 aa[2], bb[4];
#pragma unroll
        for (int mt = 0; mt < 2; ++mt) {
            const int t = mt * 16 + fr;
            aa[mt] = *(const short8*)&rTs[t * 64 + (((kk * 4 + quad) ^ (t & 7)) * 8)];
        }
#pragma unroll
        for (int nj = 0; nj < 4; ++nj)
            bb[nj] = *(const short8*)&sl[(nj * 16 + fr) * 64 + kk * 32 + quad * 8];
#pragma unroll
        for (int mt = 0; mt < 2; ++mt)
#pragma unroll
            for (int nj = 0; nj < 4; ++nj)
                y[mt][nj] = __builtin_amdgcn_mfma_f32_16x16x32_bf16(
                    aa[mt], bb[nj], y[mt][nj], 0, 0, 0);
    }
#pragma unroll
    for (int mt = 0; mt < 2; ++mt)
#pragma unroll
        for (int nj = 0; nj < 4; ++nj)
#pragma unroll
            for (int r = 0; r < 4; ++r) {
                const int t = mt * 16 + quad * 4 + r;
                const int j = nj * 16 + fr;
                vB[rowbase + (size_t)t * Cdim + j] = f2b(y[mt][nj][r]);
            }
}

// ---------------------------------------------------------------------------
// LayerNorm over C of (y + v2) -> bf16
// ---------------------------------------------------------------------------
__global__ __launch_bounds__(256) void ln_k(
    const ushort_t* __restrict__ yB, const ushort_t* __restrict__ v2,
    const float* __restrict__ gamma, const float* __restrict__ beta,
    ushort_t* __restrict__ out)
{
    const size_t base = (size_t)blockIdx.x * Cdim;
    const int tid = threadIdx.x;
    const int wave = tid >> 6, lane = tid & 63;

    float sum = 0.f, sq = 0.f;
    for (int c = tid; c < Cdim; c += 256) {
        const float s = b2f(yB[base + c]) + b2f(v2[base + c]);
        sum += s; sq += s * s;
    }
#pragma unroll
    for (int o = 1; o < 64; o <<= 1) {
        sum += __shfl_xor(sum, o);
        sq  += __shfl_xor(sq, o);
    }
    __shared__ float red[8];
    if (lane == 0) { red[wave] = sum; red[4 + wave] = sq; }
    __syncthreads();
    sum = red[0] + red[1] + red[2] + red[3];
    sq  = red[4] + red[5] + red[6] + red[7];
    const float mu  = sum * (1.f / Cdim);
    const float var = sq * (1.f / Cdim) - mu * mu;
    const float rsd = rsqrtf(var + 1e-5f);
    for (int c = tid; c < Cdim; c += 256) {
        const float s = b2f(yB[base + c]) + b2f(v2[base + c]);
        out[base + c] = f2b((s - mu) * rsd * gamma[c] + beta[c]);
    }
}

// ---------------------------------------------------------------------------
extern "C" void kernel_launch(void* const* d_in, const int* in_sizes, int n_in,
                              void* d_out, int out_size, void* d_ws, size_t ws_size,
                              hipStream_t stream)
{
    (void)in_sizes; (void)n_in; (void)out_size; (void)ws_size;
    const float* x_in   = (const float*)d_in[0];
    const float* shiftS = (const float*)d_in[1];
    const float* wkvS   = (const float*)d_in[2];
    const float* maa_r  = (const float*)d_in[3];
    const float* maa_k  = (const float*)d_in[4];
    const float* maa_v  = (const float*)d_in[5];
    const float* maa_v2 = (const float*)d_in[6];
    const float* maa_w1 = (const float*)d_in[7];
    const float* maa_w2 = (const float*)d_in[8];
    const float* maa_w  = (const float*)d_in[9];
    const float* ww1    = (const float*)d_in[10];
    const float* ww2    = (const float*)d_in[11];
    const float* tdecay = (const float*)d_in[12];
    const float* dw1    = (const float*)d_in[13];
    const float* dw2    = (const float*)d_in[14];
    const float* recep  = (const float*)d_in[16];
    const float* tkey   = (const float*)d_in[17];
    const float* valw   = (const float*)d_in[18];
    const float* outw   = (const float*)d_in[19];
    const float* gamma  = (const float*)d_in[20];
    const float* beta   = (const float*)d_in[21];

    // ---- workspace layout (~183 MB) ----
    char* ws = (char*)d_ws;
    const size_t MB = 1ull << 20;
    ushort_t* xB    = (ushort_t*)(ws + 0 * MB);     // 32 MB  x (bf16); later ew
    ushort_t* mR    = (ushort_t*)(ws + 32 * MB);    // 32 MB  r -> rT -> y_ln
    ushort_t* mK    = (ushort_t*)(ws + 64 * MB);    // 32 MB  k -> kT
    ushort_t* mV2   = (ushort_t*)(ws + 96 * MB);    // 32 MB  v2
    ushort_t* xinB  = (ushort_t*)(ws + 128 * MB);   // 32 MB  x_in bf16; later mV/y
    ushort_t* mV    = xinB;                         //        (alias: xinB dead by then)
    ushort_t* valwB = (ushort_t*)(ws + 160 * MB);   // 8 MB
    ushort_t* outwB = (ushort_t*)(ws + 168 * MB);   // 8 MB
    char* sm = ws + 176 * MB;                       // small region (~7 MB)
    ushort_t* xxx   = (ushort_t*)(sm + 0);          // 8192x128 (2 MB); later dtot
    ushort_t* mwpre = (ushort_t*)(sm + 2097152);    // 8192x32  (512 KB)
    ushort_t* gbuf  = (ushort_t*)(sm + 2621440);    // 8192x128 (2 MB)
    ushort_t* w1T   = (ushort_t*)(sm + 4718592);    // 128x2048
    ushort_t* ww1T  = (ushort_t*)(sm + 5242880);    // 32x2048
    ushort_t* dw1T  = (ushort_t*)(sm + 5373952);    // 128x2048
    ushort_t* dw2T  = (ushort_t*)(sm + 5898240);    // 2048x128
    ushort_t* ww2T  = (ushort_t*)(sm + 6422528);    // 2048x32
    ushort_t* w2T   = (ushort_t*)(sm + 6553600);    // 4x 2048x32
    ushort_t* xwB   = (ushort_t*)d_out;             // xw scratch (dead later)
    ushort_t* ewB   = xB;                           // ew over xB (xB dead)
    ushort_t* slabs = (ushort_t*)d_out;             // 64 MB slabs in d_out
    float*    dtot  = (float*)xxx;                  // 2 MB exact (xxx dead)

    const dim3 blk(256);
    const float* NF = nullptr;
    ushort_t* NUM = nullptr;
    float* NFM = nullptr;

    // 0) fp32 -> bf16 conversions + weight transposes (one launch)
    prep_k<<<dim3(29184), blk, 0, stream>>>(x_in, valw, outw, xinB, valwB, outwB,
                                            maa_w1, ww1, dw1, dw2, ww2, maa_w2,
                                            w1T, ww1T, dw1T, dw2T, ww2T, w2T);
    // 1) x = x_in @ value_w^T (bf16) — 256² 8-phase
    gemm256_k<2><<<dim3(256), dim3(512), 0, stream>>>(xinB, valwB, xB, NFM);
    // 2+3) xxx = tanh(x_in @ maa_w1); mwpre = tanh(x @ maa_w_w1) — concurrent
    tanh2_k<<<dim3(64, 2), blk, 0, stream>>>(xinB, w1T, xB, ww1T, xxx, mwpre);
    // 4) all five K=32 mix GEMMs + token-shift epilogues, fused
    mix5_k<<<dim3(64, 16), blk, 0, stream>>>(xxx, mwpre, w2T, ww2T, xB, shiftS,
                                             maa_r, maa_k, maa_v, maa_v2, maa_w,
                                             recep, tkey, mR, mK, mV, mV2, xwB);
    // 5) g = tanh(xw @ decay_w1)
    gemm_bt_k<1><<<dim3(64, 1), blk, 0, stream>>>(xwB, 2048, dw1T, 2048, 128, 2048,
                                                  gbuf, 128, NF, NUM);
    // 6) ew = exp(time_decay + g @ decay_w2) -> ewB; k *= (1 - exp(-ew))
    gemm_bt_k<3><<<dim3(64, 16), blk, 0, stream>>>(gbuf, 128, dw2T, 128, 2048, 128,
                                                   ewB, 2048, tdecay, mK);
    // 7) chunked wkv
    wkv_chunk_a<<<dim3(64, 32, 4), dim3(64), 0, stream>>>(ewB, mR, mK, mV, slabs, dtot);
    wkv_scan_b<<<dim3(8, 32, 4),   blk,      0, stream>>>(slabs, dtot, wkvS);
    wkv_chunk_c<<<dim3(64, 32, 4), dim3(64), 0, stream>>>(mR, mK, mV, slabs);
    // 8) LayerNorm(y + v2) -> y_ln (reuses mR)
    ln_k<<<dim3(8192), blk, 0, stream>>>(mV, mV2, gamma, beta, mR);
    // 9) out = y_ln @ output_w^T -> d_out as FP32 — 256² 8-phase
    gemm256_k<5><<<dim3(256), dim3(512), 0, stream>>>(mR, outwB, NUM, (float*)d_out);
}

// Round 8
// 646.569 us; speedup vs baseline: 1.1583x; 1.0020x over previous
//
#include <hip/hip_runtime.h>

// ---------------------------------------------------------------------------
// RWKV6 Tmix (B=4,T=2048,C=2048,H=32,HS=64). Inputs fp32, OUTPUT FP32.
// Round 6: chunked linear-attention wkv. Round 7: parallel chunk recurrence.
// Round 8/9: 256x256-tile 8-phase GEMM for the two K=2048 GEMMs.
// Round 10/12: mix5 fusion (round-10 epilogue). Round 11: tanh2_k merge.
// Round 13: mix5's 5 serial rounds -> grid dimension (mix1_k, grid 64x16x5):
// each block = one output's tile (stage x + one A/B pair, 1 barrier, 16 MFMA,
// epilogue). 5120 independent blocks replace the per-block round loop whose
// vmcnt(0)+barrier chain was the latency bottleneck (93us @ occ 21%, nothing
// saturated). x tile staged 5x (L3-hot, FETCH was 22MB). Bit-identical math.
// ---------------------------------------------------------------------------

#define Cdim 2048
#define Tdim 2048

using short8 = __attribute__((ext_vector_type(8))) short;   // 8 x bf16
using f32x4  = __attribute__((ext_vector_type(4))) float;
using us4    = __attribute__((ext_vector_type(4))) unsigned short;
typedef unsigned short ushort_t;

__device__ __forceinline__ float b2f(unsigned short h) {
    union { unsigned int u; float f; } x; x.u = ((unsigned int)h) << 16; return x.f;
}
__device__ __forceinline__ unsigned short f2b(float f) {
    union { float f; unsigned int u; } x; x.f = f;
    unsigned int r = x.u + 0x7fffu + ((x.u >> 16) & 1u);   // RNE
    return (unsigned short)(r >> 16);
}

__device__ __forceinline__ void gload16(const void* g, void* l) {
    __builtin_amdgcn_global_load_lds(
        (__attribute__((address_space(1))) void*)g,
        (__attribute__((address_space(3))) void*)l, 16, 0, 0);
}

// ---------------------------------------------------------------------------
// prep_k: fp32->bf16 convert (x_in, value_w, output_w) + all weight
// transposes (fp32 -> bf16 transposed), one launch.
// ---------------------------------------------------------------------------
__global__ __launch_bounds__(256) void prep_k(
    const float* __restrict__ x_in, const float* __restrict__ valw,
    const float* __restrict__ outw,
    ushort_t* __restrict__ xinB, ushort_t* __restrict__ valwB,
    ushort_t* __restrict__ outwB,
    const float* __restrict__ w1,  const float* __restrict__ ww1,
    const float* __restrict__ dw1, const float* __restrict__ dw2,
    const float* __restrict__ ww2, const float* __restrict__ w2,
    ushort_t* __restrict__ w1T,  ushort_t* __restrict__ ww1T,
    ushort_t* __restrict__ dw1T, ushort_t* __restrict__ dw2T,
    ushort_t* __restrict__ ww2T, ushort_t* __restrict__ w2T)
{
    size_t g = (size_t)blockIdx.x * 256 + threadIdx.x;
    if (g < 6291456) {
        const float* src; ushort_t* dst; size_t e;
        if (g < 4194304)      { src = x_in; dst = xinB;  e = g; }
        else if (g < 5242880) { src = valw; dst = valwB; e = g - 4194304; }
        else                  { src = outw; dst = outwB; e = g - 5242880; }
        const float4 v = ((const float4*)src)[e];
        us4 o; o.x = f2b(v.x); o.y = f2b(v.y); o.z = f2b(v.z); o.w = f2b(v.w);
        ((us4*)dst)[e] = o;
        return;
    }
    int idx = (int)(g - 6291456);
    if (idx < 262144) { int r = idx >> 7, c = idx & 127; w1T[c * 2048 + r] = f2b(w1[idx]); return; }
    idx -= 262144;
    if (idx < 65536)  { int r = idx >> 5, c = idx & 31;  ww1T[c * 2048 + r] = f2b(ww1[idx]); return; }
    idx -= 65536;
    if (idx < 262144) { int r = idx >> 7, c = idx & 127; dw1T[c * 2048 + r] = f2b(dw1[idx]); return; }
    idx -= 262144;
    if (idx < 262144) { int r = idx >> 11, c = idx & 2047; dw2T[c * 128 + r] = f2b(dw2[idx]); return; }
    idx -= 262144;
    if (idx < 65536)  { int r = idx >> 11, c = idx & 2047; ww2T[c * 32 + r] = f2b(ww2[idx]); return; }
    idx -= 65536;
    { int f = idx >> 16, rem = idx & 65535; int r = rem >> 11, c = rem & 2047;
      w2T[f * 65536 + c * 32 + r] = f2b(w2[idx]); }
}

// ---------------------------------------------------------------------------
// 256x256-tile 8-phase GEMM, M=8192 N=2048 K=2048, C = A @ B^T (both bf16
// row-major, ld=2048). MODE 2: bf16 store; MODE 5: fp32 store. (round 8/9)
// ---------------------------------------------------------------------------
template <int MODE>
__global__ __launch_bounds__(512, 2) void gemm256_k(
    const ushort_t* __restrict__ A,
    const ushort_t* __restrict__ Bw,
    ushort_t* __restrict__ outB,
    float* __restrict__ outF)
{
    __shared__ __align__(16) ushort_t lds[65536];   // A: [0,32768) B: [32768,65536)

    const int tid  = threadIdx.x;
    const int wave = tid >> 6, lane = tid & 63;
    const int wm = wave >> 2, wn = wave & 3;        // 2M x 4N wave grid
    const int fr = lane & 15, quad = lane >> 4;
    const int og8 = (((lane & 7) ^ ((lane >> 3) & 7)) * 8);

    const int id  = blockIdx.x;
    const int swz = (id & 7) * 32 + (id >> 3);
    const int mbase = (swz >> 3) * 256;             // 32 m-tiles
    const int nbase = (swz & 7) * 256;              // 8 n-tiles

    f32x4 acc[8][4];
#pragma unroll
    for (int i = 0; i < 8; ++i)
#pragma unroll
        for (int j = 0; j < 4; ++j)
#pragma unroll
            for (int r = 0; r < 4; ++r) acc[i][j][r] = 0.f;

    auto stage_half = [&](const ushort_t* __restrict__ G, int growb,
                          int dstb, int kt) {
#pragma unroll
        for (int i = 0; i < 2; ++i) {
            const int rh = i * 64 + wave * 8 + (lane >> 3);
            gload16(G + (size_t)(growb + rh) * Cdim + kt * 64 + og8,
                    &lds[dstb + (i * 512 + wave * 64) * 8]);
        }
    };

    short8 afr[4][2], bfr[2][2];

    auto LOADA = [&](int p, int mo) {
#pragma unroll
        for (int mi = 0; mi < 4; ++mi)
#pragma unroll
            for (int k = 0; k < 2; ++k) {
                const int row = wm * 128 + (mo + mi) * 16 + fr;
                afr[mi][k] = *(const short8*)
                    &lds[p + row * 64 + (((k * 4 + quad) ^ (fr & 7)) * 8)];
            }
    };
    auto LOADB = [&](int p, int no) {
#pragma unroll
        for (int ni = 0; ni < 2; ++ni)
#pragma unroll
            for (int k = 0; k < 2; ++k) {
                const int row = wn * 64 + (no + ni) * 16 + fr;
                bfr[ni][k] = *(const short8*)
                    &lds[32768 + p + row * 64 + (((k * 4 + quad) ^ (fr & 7)) * 8)];
            }
    };
    auto MFMA16 = [&](int mo, int no) {
        __builtin_amdgcn_s_setprio(1);
#pragma unroll
        for (int mi = 0; mi < 4; ++mi)
#pragma unroll
            for (int ni = 0; ni < 2; ++ni)
#pragma unroll
                for (int k = 0; k < 2; ++k)
                    acc[mo + mi][no + ni] = __builtin_amdgcn_mfma_f32_16x16x32_bf16(
                        afr[mi][k], bfr[ni][k], acc[mo + mi][no + ni], 0, 0, 0);
        __builtin_amdgcn_s_setprio(0);
    };

    // prologue: tile 0 -> buf 0
    stage_half(A,  mbase,       0,            0);
    stage_half(A,  mbase + 128, 8192,         0);
    stage_half(Bw, nbase,       32768,        0);
    stage_half(Bw, nbase + 128, 32768 + 8192, 0);

#pragma unroll 2
    for (int t = 0; t < 32; ++t) {
        const int p  = (t & 1) * 16384;      // compute buffer (element offset)
        const int q  = 16384 - p;            // stage buffer
        const int kn = (t < 31) ? t + 1 : t; // clamped prefetch tile

        // ---- P1: m[0..3] x n[0..1]; stage A(t+1) ----
        asm volatile("s_waitcnt vmcnt(0)\n\ts_barrier" ::: "memory");
        LOADA(p, 0); LOADB(p, 0);
        stage_half(A, mbase,       q,        kn);
        stage_half(A, mbase + 128, q + 8192, kn);
        asm volatile("s_barrier" ::: "memory");
        asm volatile("s_waitcnt lgkmcnt(0)" ::: "memory");
        MFMA16(0, 0);

        // ---- P2: m[0..3] x n[2..3]; stage B(t+1) ----
        asm volatile("s_barrier" ::: "memory");
        LOADB(p, 2);
        stage_half(Bw, nbase,       32768 + q,        kn);
        stage_half(Bw, nbase + 128, 32768 + q + 8192, kn);
        asm volatile("s_barrier" ::: "memory");
        asm volatile("s_waitcnt lgkmcnt(0)" ::: "memory");
        MFMA16(0, 2);

        // ---- P3: m[4..7] x n[2..3] ----
        asm volatile("s_barrier" ::: "memory");
        LOADA(p, 4);
        asm volatile("s_barrier" ::: "memory");
        asm volatile("s_waitcnt lgkmcnt(0)" ::: "memory");
        MFMA16(4, 2);

        // ---- P4: m[4..7] x n[0..1] ----
        asm volatile("s_barrier" ::: "memory");
        LOADB(p, 0);
        asm volatile("s_barrier" ::: "memory");
        asm volatile("s_waitcnt lgkmcnt(0)" ::: "memory");
        MFMA16(4, 0);
    }

    const int row0 = mbase + wm * 128 + quad * 4;
    const int col0 = nbase + wn * 64 + fr;
#pragma unroll
    for (int mi = 0; mi < 8; ++mi)
#pragma unroll
        for (int ni = 0; ni < 4; ++ni)
#pragma unroll
            for (int r = 0; r < 4; ++r) {
                const int row = row0 + mi * 16 + r;
                const int col = col0 + ni * 16;
                const size_t idx = (size_t)row * Cdim + col;
                if constexpr (MODE == 2) outB[idx] = f2b(acc[mi][ni][r]);
                else                     outF[idx] = acc[mi][ni][r];
            }
}

// ---------------------------------------------------------------------------
// mix1_k (round 13): ONE token-shift mix output per block; grid (64,16,5).
// blockIdx.z picks output o. Block stages x tile (+shifted row) and its
// {A,B} 128x32 pair, one barrier, 16 MFMA, round-10 epilogue. 5120
// independent blocks — no intra-kernel round serialization.
// Arithmetic identical to the round-10/12 mix5_k body.
// ---------------------------------------------------------------------------
__global__ __launch_bounds__(256) void mix1_k(
    const ushort_t* __restrict__ xxx,   // [8192][128] bf16
    const ushort_t* __restrict__ mwpre, // [8192][32]  bf16
    const ushort_t* __restrict__ w2T,   // 4x [2048][32] bf16
    const ushort_t* __restrict__ ww2T,  // [2048][32] bf16
    const ushort_t* __restrict__ xB,    // [8192][2048] bf16
    const float*    __restrict__ shiftS,// [4][2048] fp32
    const float* __restrict__ maa_r, const float* __restrict__ maa_k,
    const float* __restrict__ maa_v, const float* __restrict__ maa_v2,
    const float* __restrict__ maa_w,
    const float* __restrict__ recep, const float* __restrict__ tkey,
    ushort_t* __restrict__ mR,  ushort_t* __restrict__ mK,
    ushort_t* __restrict__ mV,  ushort_t* __restrict__ mV2,
    ushort_t* __restrict__ xwB)
{
    __shared__ __align__(16) ushort_t xs[129 * 136];   // [1+row][col], pad 136
    __shared__ __align__(16) ushort_t abuf[128 * 32];
    __shared__ __align__(16) ushort_t bbuf[128 * 32];

    const int tid  = threadIdx.x;
    const int wave = tid >> 6, lane = tid & 63;
    const int wm = wave >> 1, wn = wave & 1;
    const int fr = lane & 15, quad = lane >> 4;

    const int mbase = blockIdx.x * 128;
    const int nbase = blockIdx.y * 128;
    const int o  = blockIdx.z;           // which of the 5 outputs
    const int b  = mbase >> 11;          // batch
    const int t0 = mbase & 2047;         // first t of tile

    // per-output sources
    const ushort_t* asrc[5] = {xxx, xxx + 32, xxx + 64, xxx + 96, mwpre};
    const int       alda[5] = {128, 128, 128, 128, 32};
    const ushort_t* bsrc[5] = {w2T, w2T + 65536, w2T + 131072, w2T + 196608, ww2T};
    const float*    cvec[5] = {maa_r, maa_k, maa_v, maa_v2, maa_w};
    const float*    cmul[5] = {recep, tkey, nullptr, nullptr, nullptr};
    ushort_t*       outs[5] = {mR, mK, mV, mV2, xwB};

    // ---- stage A_o/B_o 128x32 (issue first: earliest in flight) ----
    // linear LDS dest, source octet pre-swizzled (phys oct = oct ^ (row&3))
#pragma unroll
    for (int i = 0; i < 2; ++i) {
        const int slot = i * 256 + tid;      // [0,512)
        const int r = slot >> 2, oct = slot & 3;
        const int sw = ((oct ^ (r & 3)) * 8);
        gload16(asrc[o] + (size_t)(mbase + r) * alda[o] + sw, &abuf[slot * 8]);
        gload16(bsrc[o] + (size_t)(nbase + r) * 32 + sw,      &bbuf[slot * 8]);
    }

    // ---- stage x tile: xs[1+r][c] = xB[mbase+r][nbase+c], 16B granules ----
#pragma unroll
    for (int it = 0; it < 8; ++it) {
        const int idx = it * 256 + tid;          // [0,2048)
        const int r = idx >> 4, c8 = (idx & 15) * 8;
        *(short8*)&xs[(r + 1) * 136 + c8] =
            *(const short8*)&xB[(size_t)(mbase + r) * Cdim + nbase + c8];
    }
    // shifted row (xp for local row 0): fp32 shiftS handled in epilogue
    if (tid < 128)
        xs[tid] = (t0 > 0) ? xB[(size_t)(mbase - 1) * Cdim + nbase + tid]
                           : f2b(shiftS[(size_t)b * Cdim + nbase + tid]);

    __syncthreads();    // drains vmcnt (gload_lds) + lgkmcnt (xs ds_writes)

    const int row0l = wm * 64 + quad * 4;
    const int col0l = wn * 64 + fr;

    // ---- fragments from abuf/bbuf ----
    short8 af[4], bf[4];
#pragma unroll
    for (int mi = 0; mi < 4; ++mi) {
        const int r = wm * 64 + mi * 16 + fr;
        af[mi] = *(const short8*)&abuf[r * 32 + ((quad ^ (r & 3)) * 8)];
    }
#pragma unroll
    for (int ni = 0; ni < 4; ++ni) {
        const int r = wn * 64 + ni * 16 + fr;
        bf[ni] = *(const short8*)&bbuf[r * 32 + ((quad ^ (r & 3)) * 8)];
    }

    f32x4 acc[4][4];
#pragma unroll
    for (int mi = 0; mi < 4; ++mi)
#pragma unroll
        for (int ni = 0; ni < 4; ++ni) {
#pragma unroll
            for (int r = 0; r < 4; ++r) acc[mi][ni][r] = 0.f;
            acc[mi][ni] = __builtin_amdgcn_mfma_f32_16x16x32_bf16(
                af[mi], bf[ni], acc[mi][ni], 0, 0, 0);
        }

    // ---- epilogue: val = x + (xp-x)*(cvec+acc) [*cmul] ----
    const float* cv = cvec[o];
    const float* cm = cmul[o];
    ushort_t* op = outs[o];
#pragma unroll
    for (int mi = 0; mi < 4; ++mi)
#pragma unroll
        for (int ni = 0; ni < 4; ++ni)
#pragma unroll
            for (int r = 0; r < 4; ++r) {
                const int lr = row0l + mi * 16 + r;
                const int lc = col0l + ni * 16;
                const int col = nbase + lc;
                const float x  = b2f(xs[(lr + 1) * 136 + lc]);
                const float xp = (lr == 0 && t0 == 0)
                                     ? shiftS[(size_t)b * Cdim + col]
                                     : b2f(xs[lr * 136 + lc]);
                float val = x + (xp - x) * (cv[col] + acc[mi][ni][r]);
                if (cm) val *= cm[col];
                op[(size_t)(mbase + lr) * Cdim + col] = f2b(val);
            }
}

// ---------------------------------------------------------------------------
// tanh2_k: the two skinny tanh GEMMs in one launch, grid (64,2). (round 11)
// by=0: xxx  = tanh(x_in @ maa_w1)   N=128, ldc=128
// by=1: mwpre= tanh(x    @ maa_w_w1) N=32,  ldc=32
// ---------------------------------------------------------------------------
__global__ __launch_bounds__(256) void tanh2_k(
    const ushort_t* __restrict__ xinB, const ushort_t* __restrict__ w1T,
    const ushort_t* __restrict__ xB,   const ushort_t* __restrict__ ww1T,
    ushort_t* __restrict__ xxx, ushort_t* __restrict__ mwpre)
{
    const int by = blockIdx.y;
    const ushort_t* A  = by ? xB    : xinB;
    const ushort_t* Bw = by ? ww1T  : w1T;
    ushort_t* out      = by ? mwpre : xxx;
    const int N        = by ? 32 : 128;
    const int ldc      = N;

    __shared__ __align__(16) ushort_t At[128 * 32];
    __shared__ __align__(16) ushort_t Bt[128 * 32];

    const int tid  = threadIdx.x;
    const int wave = tid >> 6, lane = tid & 63;
    const int wm = wave >> 1, wn = wave & 1;
    const int fr = lane & 15, quad = lane >> 4;
    const int cr = lane >> 2;
    const int cc = (lane & 3) * 8;

    f32x4 acc[4][4];
#pragma unroll
    for (int i = 0; i < 4; ++i)
#pragma unroll
        for (int j = 0; j < 4; ++j)
#pragma unroll
            for (int r = 0; r < 4; ++r) acc[i][j][r] = 0.f;

    const int mbase = blockIdx.x * 128;

    for (int k0 = 0; k0 < 2048; k0 += 32) {
        __syncthreads();
#pragma unroll
        for (int c2 = 0; c2 < 2; ++c2) {
            const int q  = wave * 2 + c2;
            const int ar = mbase + q * 16 + cr;
            gload16(A + (size_t)ar * 2048 + k0 + cc, &At[q * 512]);
            int br = q * 16 + cr;
            br = br < N ? br : N - 1;   // clamp for skinny-N
            gload16(Bw + (size_t)br * 2048 + k0 + cc, &Bt[q * 512]);
        }
        __syncthreads();

        short8 af[4], bfr[4];
#pragma unroll
        for (int mi = 0; mi < 4; ++mi)
            af[mi] = *(const short8*)&At[(wm * 64 + mi * 16 + fr) * 32 + quad * 8];
#pragma unroll
        for (int ni = 0; ni < 4; ++ni)
            bfr[ni] = *(const short8*)&Bt[(wn * 64 + ni * 16 + fr) * 32 + quad * 8];
#pragma unroll
        for (int mi = 0; mi < 4; ++mi)
#pragma unroll
            for (int ni = 0; ni < 4; ++ni)
                acc[mi][ni] = __builtin_amdgcn_mfma_f32_16x16x32_bf16(
                    af[mi], bfr[ni], acc[mi][ni], 0, 0, 0);
    }

    const int row0 = mbase + wm * 64 + quad * 4;
    const int col0 = wn * 64 + fr;
#pragma unroll
    for (int mi = 0; mi < 4; ++mi)
#pragma unroll
        for (int ni = 0; ni < 4; ++ni) {
            const int col = col0 + ni * 16;
#pragma unroll
            for (int r = 0; r < 4; ++r) {
                const int row = row0 + mi * 16 + r;
                if (col < N)
                    out[(size_t)row * ldc + col] = f2b(tanhf(acc[mi][ni][r]));
            }
        }
}

// ---------------------------------------------------------------------------
// BT GEMM (128-tile): MODE 1: tanh (guarded); MODE 3: decay fuse.
// ---------------------------------------------------------------------------
template <int MODE>
__global__ __launch_bounds__(256) void gemm_bt_k(
    const ushort_t* __restrict__ A, int lda,
    const ushort_t* __restrict__ Bw, int ldb,
    int N, int K,
    ushort_t* __restrict__ outB, int ldc,
    const float* __restrict__ cvec,
    ushort_t* __restrict__ inplace)
{
    __shared__ __align__(16) ushort_t At[128 * 32];
    __shared__ __align__(16) ushort_t Bt[128 * 32];

    const int tid  = threadIdx.x;
    const int wave = tid >> 6, lane = tid & 63;
    const int wm = wave >> 1, wn = wave & 1;
    const int fr = lane & 15, quad = lane >> 4;
    const int cr = lane >> 2;
    const int cc = (lane & 3) * 8;

    f32x4 acc[4][4];
#pragma unroll
    for (int i = 0; i < 4; ++i)
#pragma unroll
        for (int j = 0; j < 4; ++j)
#pragma unroll
            for (int r = 0; r < 4; ++r) acc[i][j][r] = 0.f;

    const int mbase = blockIdx.x * 128;
    const int nbase = blockIdx.y * 128;

    for (int k0 = 0; k0 < K; k0 += 32) {
        __syncthreads();
#pragma unroll
        for (int c2 = 0; c2 < 2; ++c2) {
            const int q  = wave * 2 + c2;
            const int ar = mbase + q * 16 + cr;
            gload16(A + (size_t)ar * lda + k0 + cc, &At[q * 512]);
            int br = nbase + q * 16 + cr;
            br = br < N ? br : N - 1;
            gload16(Bw + (size_t)br * ldb + k0 + cc, &Bt[q * 512]);
        }
        __syncthreads();

        short8 af[4], bfr[4];
#pragma unroll
        for (int mi = 0; mi < 4; ++mi)
            af[mi] = *(const short8*)&At[(wm * 64 + mi * 16 + fr) * 32 + quad * 8];
#pragma unroll
        for (int ni = 0; ni < 4; ++ni)
            bfr[ni] = *(const short8*)&Bt[(wn * 64 + ni * 16 + fr) * 32 + quad * 8];
#pragma unroll
        for (int mi = 0; mi < 4; ++mi)
#pragma unroll
            for (int ni = 0; ni < 4; ++ni)
                acc[mi][ni] = __builtin_amdgcn_mfma_f32_16x16x32_bf16(
                    af[mi], bfr[ni], acc[mi][ni], 0, 0, 0);
    }

    const int row0 = mbase + wm * 64 + quad * 4;
    const int col0 = nbase + wn * 64 + fr;
#pragma unroll
    for (int mi = 0; mi < 4; ++mi) {
#pragma unroll
        for (int ni = 0; ni < 4; ++ni) {
            const int col = col0 + ni * 16;
#pragma unroll
            for (int r = 0; r < 4; ++r) {
                const int row = row0 + mi * 16 + r;
                const float v = acc[mi][ni][r];
                const size_t idx = (size_t)row * ldc + col;
                if constexpr (MODE == 1) {
                    if (col < N) outB[idx] = f2b(tanhf(v));
                } else {  // MODE 3
                    const float w  = cvec[col] + v;
                    const float ew = __expf(w);
                    outB[idx] = f2b(ew);
                    inplace[idx] = f2b(b2f(inplace[idx]) * (1.f - __expf(-ew)));
                }
            }
        }
    }
}

// ---------------------------------------------------------------------------
// Chunked WKV, pass A (parallel over b,h,chunk; 1 wave/block).
// ---------------------------------------------------------------------------
__global__ __launch_bounds__(64) void wkv_chunk_a(
    const ushort_t* __restrict__ ewB,
    ushort_t* rB, ushort_t* kB,
    const ushort_t* __restrict__ vB,
    ushort_t* __restrict__ uOut, float* __restrict__ dtot)
{
    const int c = blockIdx.x, h = blockIdx.y, b = blockIdx.z;
    const int lane = threadIdx.x;
    const int fr = lane & 15, quad = lane >> 4;
    __shared__ __align__(16) ushort_t kTT[64 * 40];
    __shared__ __align__(16) ushort_t vT [64 * 40];

    const size_t rowbase = ((size_t)b * Tdim + c * 32) * Cdim + h * 64;

    float Lrun = 0.f;                       // L_t for channel i=lane
    for (int t = 0; t < 32; ++t) {
        const size_t off = rowbase + (size_t)t * Cdim + lane;
        const float e  = b2f(ewB[off]);     // ew_t ; log d_t = -e
        const float rv = b2f(rB[off]);
        const float kv = b2f(kB[off]);
        const ushort_t rT = f2b(rv * __expf(Lrun));
        const ushort_t kT = f2b(kv * __expf(e - Lrun));   // e^{-L_{t+1}}
        rB[off] = rT;
        kB[off] = kT;
        kTT[lane * 40 + t] = kT;
        vT [lane * 40 + t] = vB[off];       // raw bf16 copy
        Lrun -= e;
    }
    const int slab = (b * 32 + h) * 64 + c;
    dtot[(size_t)slab * 64 + lane] = __expf(Lrun);
    __syncthreads();

    short8 af[4], bf[4];
#pragma unroll
    for (int mj = 0; mj < 4; ++mj)
        af[mj] = *(const short8*)&vT[(mj * 16 + fr) * 40 + quad * 8];
#pragma unroll
    for (int ni = 0; ni < 4; ++ni)
        bf[ni] = *(const short8*)&kTT[(ni * 16 + fr) * 40 + quad * 8];

    ushort_t* uo = uOut + (size_t)slab * 4096;
#pragma unroll
    for (int mj = 0; mj < 4; ++mj) {
#pragma unroll
        for (int ni = 0; ni < 4; ++ni) {
            f32x4 acc = {0.f, 0.f, 0.f, 0.f};
            acc = __builtin_amdgcn_mfma_f32_16x16x32_bf16(af[mj], bf[ni], acc, 0, 0, 0);
#pragma unroll
            for (int r = 0; r < 4; ++r) {
                const int j = mj * 16 + quad * 4 + r;   // C/D: row=quad*4+r
                const int i = ni * 16 + fr;             //      col=fr
                uo[j * 64 + i] = f2b(acc[r]);
            }
        }
    }
}

// ---------------------------------------------------------------------------
// Chunked WKV, pass B: per-scalar-thread chunk recurrence.
// ---------------------------------------------------------------------------
__global__ __launch_bounds__(256) void wkv_scan_b(
    ushort_t* __restrict__ slabs, const float* __restrict__ dtot,
    const float* __restrict__ s0)
{
    const int jhi = blockIdx.x, h = blockIdx.y, b = blockIdx.z;
    const int tid = threadIdx.x;
    const int ip = tid & 31, jl = tid >> 5;
    const int i0 = ip * 2;
    const int j  = jhi * 8 + jl;
    const size_t bh = (size_t)(b * 32 + h);
    const size_t base = bh * 64;                 // first slab of this (b,h)

    __shared__ float dsh[64 * 64];               // [c][i]
    for (int e = tid; e < 4096; e += 256) dsh[e] = dtot[base * 64 + e];

    const float* sp = s0 + bh * 4096;            // [i][j] fp32
    float sa = sp[i0 * 64 + j];
    float sb = sp[(i0 + 1) * 64 + j];
    __syncthreads();

    unsigned int* up =
        (unsigned int*)(slabs + base * 4096 + (size_t)j * 64 + i0);
#pragma unroll 8
    for (int c = 0; c < 64; ++c) {
        const unsigned int u = up[(size_t)c * 2048];
        const float2 dt = *(const float2*)&dsh[c * 64 + i0];
        const unsigned int pre =
            (unsigned int)f2b(sa) | ((unsigned int)f2b(sb) << 16);
        sa = dt.x * (sa + b2f((ushort_t)(u & 0xffffu)));
        sb = dt.y * (sb + b2f((ushort_t)(u >> 16)));
        up[(size_t)c * 2048] = pre;              // write PRE-chunk state
    }
}

// ---------------------------------------------------------------------------
// Chunked WKV, pass C (parallel over b,h,chunk; 1 wave/block).
// ---------------------------------------------------------------------------
__global__ __launch_bounds__(64) void wkv_chunk_c(
    const ushort_t* __restrict__ rB, const ushort_t* __restrict__ kB,
    ushort_t* vB, const ushort_t* __restrict__ slabs)
{
    const int c = blockIdx.x, h = blockIdx.y, b = blockIdx.z;
    const int lane = threadIdx.x;
    const int fr = lane & 15, quad = lane >> 4;
    __shared__ __align__(16) ushort_t rTs[32 * 64];   // [t][i^swz]
    __shared__ __align__(16) ushort_t kTs[32 * 64];   // [s][i^swz]
    __shared__ __align__(16) ushort_t vTs[64 * 40];   // [j][t], pad 40
    __shared__ __align__(16) ushort_t Ams[32 * 32];   // masked A, [t][s]

    const size_t rowbase = ((size_t)b * Tdim + c * 32) * Cdim + h * 64;

#pragma unroll
    for (int it = 0; it < 4; ++it) {
        const int idx = it * 64 + lane;           // 0..255
        const int t = idx >> 3, oct = idx & 7;
        const size_t g = rowbase + (size_t)t * Cdim + oct * 8;
        const int sw = ((oct ^ (t & 7)) * 8);
        *(short8*)&rTs[t * 64 + sw] = *(const short8*)&rB[g];
        *(short8*)&kTs[t * 64 + sw] = *(const short8*)&kB[g];
    }
    for (int t = 0; t < 32; ++t)
        vTs[lane * 40 + t] = vB[rowbase + (size_t)t * Cdim + lane];
    __syncthreads();

    f32x4 aacc[2][2];
#pragma unroll
    for (int mt = 0; mt < 2; ++mt)
#pragma unroll
        for (int st = 0; st < 2; ++st)
#pragma unroll
            for (int r = 0; r < 4; ++r) aacc[mt][st][r] = 0.f;

#pragma unroll
    for (int kk = 0; kk < 2; ++kk) {
        short8 ra[2], kb2[2];
#pragma unroll
        for (int mt = 0; mt < 2; ++mt) {
            const int t = mt * 16 + fr;
            ra[mt] = *(const short8*)&rTs[t * 64 + (((kk * 4 + quad) ^ (t & 7)) * 8)];
        }
#pragma unroll
        for (int st = 0; st < 2; ++st) {
            const int s = st * 16 + fr;
            kb2[st] = *(const short8*)&kTs[s * 64 + (((kk * 4 + quad) ^ (s & 7)) * 8)];
        }
#pragma unroll
        for (int mt = 0; mt < 2; ++mt)
#pragma unroll
            for (int st = 0; st < 2; ++st)
                aacc[mt][st] = __builtin_amdgcn_mfma_f32_16x16x32_bf16(
                    ra[mt], kb2[st], aacc[mt][st], 0, 0, 0);
    }

#pragma unroll
    for (int mt = 0; mt < 2; ++mt)
#pragma unroll
        for (int st = 0; st < 2; ++st)
#pragma unroll
            for (int r = 0; r < 4; ++r) {
                const int t = mt * 16 + quad * 4 + r;
                const int s = st * 16 + fr;
                Ams[t * 32 + s] = (t > s) ? f2b(aacc[mt][st][r]) : (ushort_t)0;
            }
    __syncthreads();

    f32x4 y[2][4];
#pragma unroll
    for (int mt = 0; mt < 2; ++mt)
#pragma unroll
        for (int nj = 0; nj < 4; ++nj)
#pragma unroll
            for (int r = 0; r < 4; ++r) y[mt][nj][r] = 0.f;

    {
        short8 aa[2], bb[4];
#pragma unroll
        for (int mt = 0; mt < 2; ++mt)
            aa[mt] = *(const short8*)&Ams[(mt * 16 + fr) * 32 + quad * 8];
#pragma unroll
        for (int nj = 0; nj < 4; ++nj)
            bb[nj] = *(const short8*)&vTs[(nj * 16 + fr) * 40 + quad * 8];
#pragma unroll
        for (int mt = 0; mt < 2; ++mt)
#pragma unroll
            for (int nj = 0; nj < 4; ++nj)
                y[mt][nj] = __builtin_amdgcn_mfma_f32_16x16x32_bf16(
                    aa[mt], bb[nj], y[mt][nj], 0, 0, 0);
    }
    const ushort_t* sl = slabs + (size_t)((b * 32 + h) * 64 + c) * 4096;
#pragma unroll
    for (int kk = 0; kk < 2; ++kk) {
        short8 aa[2], bb[4];
#pragma unroll
        for (int mt = 0; mt < 2; ++mt) {
            const int t = mt * 16 + fr;
            aa[mt] = *(const short8*)&rTs[t * 64 + (((kk * 4 + quad) ^ (t & 7)) * 8)];
        }
#pragma unroll
        for (int nj = 0; nj < 4; ++nj)
            bb[nj] = *(const short8*)&sl[(nj * 16 + fr) * 64 + kk * 32 + quad * 8];
#pragma unroll
        for (int mt = 0; mt < 2; ++mt)
#pragma unroll
            for (int nj = 0; nj < 4; ++nj)
                y[mt][nj] = __builtin_amdgcn_mfma_f32_16x16x32_bf16(
                    aa[mt], bb[nj], y[mt][nj], 0, 0, 0);
    }
#pragma unroll
    for (int mt = 0; mt < 2; ++mt)
#pragma unroll
        for (int nj = 0; nj < 4; ++nj)
#pragma unroll
            for (int r = 0; r < 4; ++r) {
                const int t = mt * 16 + quad * 4 + r;
                const int j = nj * 16 + fr;
                vB[rowbase + (size_t)t * Cdim + j] = f2b(y[mt][nj][r]);
            }
}

// ---------------------------------------------------------------------------
// LayerNorm over C of (y + v2) -> bf16
// ---------------------------------------------------------------------------
__global__ __launch_bounds__(256) void ln_k(
    const ushort_t* __restrict__ yB, const ushort_t* __restrict__ v2,
    const float* __restrict__ gamma, const float* __restrict__ beta,
    ushort_t* __restrict__ out)
{
    const size_t base = (size_t)blockIdx.x * Cdim;
    const int tid = threadIdx.x;
    const int wave = tid >> 6, lane = tid & 63;

    float sum = 0.f, sq = 0.f;
    for (int c = tid; c < Cdim; c += 256) {
        const float s = b2f(yB[base + c]) + b2f(v2[base + c]);
        sum += s; sq += s * s;
    }
#pragma unroll
    for (int o = 1; o < 64; o <<= 1) {
        sum += __shfl_xor(sum, o);
        sq  += __shfl_xor(sq, o);
    }
    __shared__ float red[8];
    if (lane == 0) { red[wave] = sum; red[4 + wave] = sq; }
    __syncthreads();
    sum = red[0] + red[1] + red[2] + red[3];
    sq  = red[4] + red[5] + red[6] + red[7];
    const float mu  = sum * (1.f / Cdim);
    const float var = sq * (1.f / Cdim) - mu * mu;
    const float rsd = rsqrtf(var + 1e-5f);
    for (int c = tid; c < Cdim; c += 256) {
        const float s = b2f(yB[base + c]) + b2f(v2[base + c]);
        out[base + c] = f2b((s - mu) * rsd * gamma[c] + beta[c]);
    }
}

// ---------------------------------------------------------------------------
extern "C" void kernel_launch(void* const* d_in, const int* in_sizes, int n_in,
                              void* d_out, int out_size, void* d_ws, size_t ws_size,
                              hipStream_t stream)
{
    (void)in_sizes; (void)n_in; (void)out_size; (void)ws_size;
    const float* x_in   = (const float*)d_in[0];
    const float* shiftS = (const float*)d_in[1];
    const float* wkvS   = (const float*)d_in[2];
    const float* maa_r  = (const float*)d_in[3];
    const float* maa_k  = (const float*)d_in[4];
    const float* maa_v  = (const float*)d_in[5];
    const float* maa_v2 = (const float*)d_in[6];
    const float* maa_w1 = (const float*)d_in[7];
    const float* maa_w2 = (const float*)d_in[8];
    const float* maa_w  = (const float*)d_in[9];
    const float* ww1    = (const float*)d_in[10];
    const float* ww2    = (const float*)d_in[11];
    const float* tdecay = (const float*)d_in[12];
    const float* dw1    = (const float*)d_in[13];
    const float* dw2    = (const float*)d_in[14];
    const float* recep  = (const float*)d_in[16];
    const float* tkey   = (const float*)d_in[17];
    const float* valw   = (const float*)d_in[18];
    const float* outw   = (const float*)d_in[19];
    const float* gamma  = (const float*)d_in[20];
    const float* beta   = (const float*)d_in[21];

    // ---- workspace layout (~183 MB) ----
    char* ws = (char*)d_ws;
    const size_t MB = 1ull << 20;
    ushort_t* xB    = (ushort_t*)(ws + 0 * MB);     // 32 MB  x (bf16); later ew
    ushort_t* mR    = (ushort_t*)(ws + 32 * MB);    // 32 MB  r -> rT -> y_ln
    ushort_t* mK    = (ushort_t*)(ws + 64 * MB);    // 32 MB  k -> kT
    ushort_t* mV2   = (ushort_t*)(ws + 96 * MB);    // 32 MB  v2
    ushort_t* xinB  = (ushort_t*)(ws + 128 * MB);   // 32 MB  x_in bf16; later mV/y
    ushort_t* mV    = xinB;                         //        (alias: xinB dead by then)
    ushort_t* valwB = (ushort_t*)(ws + 160 * MB);   // 8 MB
    ushort_t* outwB = (ushort_t*)(ws + 168 * MB);   // 8 MB
    char* sm = ws + 176 * MB;                       // small region (~7 MB)
    ushort_t* xxx   = (ushort_t*)(sm + 0);          // 8192x128 (2 MB); later dtot
    ushort_t* mwpre = (ushort_t*)(sm + 2097152);    // 8192x32  (512 KB)
    ushort_t* gbuf  = (ushort_t*)(sm + 2621440);    // 8192x128 (2 MB)
    ushort_t* w1T   = (ushort_t*)(sm + 4718592);    // 128x2048
    ushort_t* ww1T  = (ushort_t*)(sm + 5242880);    // 32x2048
    ushort_t* dw1T  = (ushort_t*)(sm + 5373952);    // 128x2048
    ushort_t* dw2T  = (ushort_t*)(sm + 5898240);    // 2048x128
    ushort_t* ww2T  = (ushort_t*)(sm + 6422528);    // 2048x32
    ushort_t* w2T   = (ushort_t*)(sm + 6553600);    // 4x 2048x32
    ushort_t* xwB   = (ushort_t*)d_out;             // xw scratch (dead later)
    ushort_t* ewB   = xB;                           // ew over xB (xB dead)
    ushort_t* slabs = (ushort_t*)d_out;             // 64 MB slabs in d_out
    float*    dtot  = (float*)xxx;                  // 2 MB exact (xxx dead)

    const dim3 blk(256);
    const float* NF = nullptr;
    ushort_t* NUM = nullptr;
    float* NFM = nullptr;

    // 0) fp32 -> bf16 conversions + weight transposes (one launch)
    prep_k<<<dim3(29184), blk, 0, stream>>>(x_in, valw, outw, xinB, valwB, outwB,
                                            maa_w1, ww1, dw1, dw2, ww2, maa_w2,
                                            w1T, ww1T, dw1T, dw2T, ww2T, w2T);
    // 1) x = x_in @ value_w^T (bf16) — 256² 8-phase
    gemm256_k<2><<<dim3(256), dim3(512), 0, stream>>>(xinB, valwB, xB, NFM);
    // 2+3) xxx = tanh(x_in @ maa_w1); mwpre = tanh(x @ maa_w_w1) — concurrent
    tanh2_k<<<dim3(64, 2), blk, 0, stream>>>(xinB, w1T, xB, ww1T, xxx, mwpre);
    // 4) five K=32 mix GEMMs + token-shift epilogues; one output per block
    mix1_k<<<dim3(64, 16, 5), blk, 0, stream>>>(xxx, mwpre, w2T, ww2T, xB, shiftS,
                                                maa_r, maa_k, maa_v, maa_v2, maa_w,
                                                recep, tkey, mR, mK, mV, mV2, xwB);
    // 5) g = tanh(xw @ decay_w1)
    gemm_bt_k<1><<<dim3(64, 1), blk, 0, stream>>>(xwB, 2048, dw1T, 2048, 128, 2048,
                                                  gbuf, 128, NF, NUM);
    // 6) ew = exp(time_decay + g @ decay_w2) -> ewB; k *= (1 - exp(-ew))
    gemm_bt_k<3><<<dim3(64, 16), blk, 0, stream>>>(gbuf, 128, dw2T, 128, 2048, 128,
                                                   ewB, 2048, tdecay, mK);
    // 7) chunked wkv
    wkv_chunk_a<<<dim3(64, 32, 4), dim3(64), 0, stream>>>(ewB, mR, mK, mV, slabs, dtot);
    wkv_scan_b<<<dim3(8, 32, 4),   blk,      0, stream>>>(slabs, dtot, wkvS);
    wkv_chunk_c<<<dim3(64, 32, 4), dim3(64), 0, stream>>>(mR, mK, mV, slabs);
    // 8) LayerNorm(y + v2) -> y_ln (reuses mR)
    ln_k<<<dim3(8192), blk, 0, stream>>>(mV, mV2, gamma, beta, mR);
    // 9) out = y_ln @ output_w^T -> d_out as FP32 — 256² 8-phase
    gemm256_k<5><<<dim3(256), dim3(512), 0, stream>>>(mR, outwB, NUM, (float*)d_out);
}